// Round 10
// baseline (620.192 us; speedup 1.0000x reference)
//
#include <hip/hip_runtime.h>
#include <hip/hip_bf16.h>

#define N_NODES 100000
#define N_EDGES 1600000
#define D_NODE 128
#define D_EDGE 64
#define D_MSG 128
#define K1 192   // NODE_DIM + EDGE_DIM
#define K2 256   // NODE_DIM + MSG_DIM
#define D_OUT 128
#define NSB 98   // scan blocks: ceil(100000/1024)
#define TILE 64
#define NT (N_EDGES / TILE)   // 25000 exact

using frag8 = __attribute__((ext_vector_type(8))) short;   // 8 bf16 (4 VGPRs)
using facc  = __attribute__((ext_vector_type(4))) float;   // 4 f32 acc
typedef int   i32x4 __attribute__((ext_vector_type(4)));
typedef float f32x4 __attribute__((ext_vector_type(4)));
typedef float f32x2 __attribute__((ext_vector_type(2)));

static __device__ __forceinline__ unsigned short f2bf(float f) {
    unsigned int u = __float_as_uint(f);
    u = u + 0x7fffu + ((u >> 16) & 1u);   // RNE
    return (unsigned short)(u >> 16);
}
static __device__ __forceinline__ float bflo(unsigned int u) { return __uint_as_float(u << 16); }
static __device__ __forceinline__ float bfhi(unsigned int u) { return __uint_as_float(u & 0xffff0000u); }

union F8 { unsigned short s[8]; frag8 f; uint4 u4; };

static __device__ __forceinline__ frag8 pack8(float4 a, float4 b) {
    F8 u;
    u.s[0] = f2bf(a.x); u.s[1] = f2bf(a.y); u.s[2] = f2bf(a.z); u.s[3] = f2bf(a.w);
    u.s[4] = f2bf(b.x); u.s[5] = f2bf(b.y); u.s[6] = f2bf(b.z); u.s[7] = f2bf(b.w);
    return u.f;
}
static __device__ __forceinline__ frag8 pack8v(f32x4 a, f32x4 b) {
    F8 u;
    u.s[0] = f2bf(a[0]); u.s[1] = f2bf(a[1]); u.s[2] = f2bf(a[2]); u.s[3] = f2bf(a[3]);
    u.s[4] = f2bf(b[0]); u.s[5] = f2bf(b[1]); u.s[6] = f2bf(b[2]); u.s[7] = f2bf(b[3]);
    return u.f;
}

// ---------------------------------------------------------------------------
// prep_all: W transpose->bf16, node_emb->bf16, dst histogram. One launch.
// ---------------------------------------------------------------------------
__global__ void prep_all_kernel(const float* __restrict__ Wm, const float* __restrict__ Wu,
                                const float* __restrict__ node_emb, const int* __restrict__ dst,
                                unsigned short* __restrict__ WtM, unsigned short* __restrict__ WtU,
                                unsigned int* __restrict__ nodeB32, int* __restrict__ cnt) {
    int idx0 = blockIdx.x * blockDim.x + threadIdx.x;
    int stride = gridDim.x * blockDim.x;
    for (int idx = idx0; idx < 128 * K1; idx += stride) {
        int o = idx / K1, k = idx - o * K1;
        WtM[idx] = f2bf(Wm[k * D_MSG + o]);
    }
    for (int idx = idx0; idx < 128 * K2; idx += stride) {
        int o = idx >> 8, k = idx & 255;
        WtU[idx] = f2bf(Wu[k * D_OUT + o]);
    }
    const int total = N_NODES * 64;   // u32 pairs
    for (int i = idx0; i < total; i += stride) {
        float2 v = *(const float2*)&node_emb[(size_t)i * 2];
        nodeB32[i] = (unsigned)f2bf(v.x) | ((unsigned)f2bf(v.y) << 16);
    }
    for (int e = idx0; e < N_EDGES; e += stride) {
        int d = min(max(dst[e], 0), N_NODES - 1);
        atomicAdd(&cnt[d], 1);
    }
}

__global__ __launch_bounds__(1024) void scan_blocks(const int* __restrict__ cnt,
                                                    int* __restrict__ base,
                                                    int* __restrict__ part) {
    __shared__ int sh[1024];
    int i = blockIdx.x * 1024 + threadIdx.x;
    int c = (i < N_NODES) ? cnt[i] : 0;
    sh[threadIdx.x] = c;
    __syncthreads();
    for (int s = 1; s < 1024; s <<= 1) {
        int t = (threadIdx.x >= s) ? sh[threadIdx.x - s] : 0;
        __syncthreads();
        sh[threadIdx.x] += t;
        __syncthreads();
    }
    if (i < N_NODES) base[i] = sh[threadIdx.x] - c;   // exclusive within block
    if (threadIdx.x == 1023) part[blockIdx.x] = sh[1023];   // raw block sum
}

// scan_add: computes this block's partial-prefix in-wave (no scan_partials pass)
__global__ __launch_bounds__(1024) void scan_add(int* __restrict__ base, const int* __restrict__ part) {
    __shared__ int soff;
    if (threadIdx.x < 64) {
        int l = threadIdx.x;
        int v = 0;
        if (l < blockIdx.x) v += part[l];
        if (l + 64 < blockIdx.x) v += part[l + 64];
#pragma unroll
        for (int s = 32; s; s >>= 1) v += __shfl_down(v, s, 64);
        if (l == 0) soff = v;
    }
    __syncthreads();
    int i = blockIdx.x * 1024 + threadIdx.x;
    if (i < N_NODES) base[i] += soff;
}

// ---------------------------------------------------------------------------
// scatter: bins edges by dst; ONE packed int4 nt-store per edge
// meta[pos] = {orig_e, src[e], d, 0}
// ---------------------------------------------------------------------------
__global__ void scatter_kernel(const int* __restrict__ dst, const int* __restrict__ src,
                               const int* __restrict__ base, int* __restrict__ cursor,
                               i32x4* __restrict__ meta) {
    int idx0 = blockIdx.x * blockDim.x + threadIdx.x;
    int stride = gridDim.x * blockDim.x;
    for (int e = idx0; e < N_EDGES; e += stride) {
        int d = min(max(dst[e], 0), N_NODES - 1);
        int pos = base[d] + atomicAdd(&cursor[d], 1);
        i32x4 m; m[0] = e; m[1] = src[e]; m[2] = d; m[3] = 0;
        __builtin_nontemporal_store(m, &meta[pos]);
    }
}

// ---------------------------------------------------------------------------
// FUSED Phase A: per 64-edge tile: msg GEMM (W in regs, inputs staged in
// XOR-swizzled LDS) -> msg tile in LDS -> in-block per-node mean.
// Streaming data (edge rows, meta, mean/spill stores) uses NON-TEMPORAL
// ops so the nodeB gather working set stays L2-resident.
// ---------------------------------------------------------------------------
__global__ __launch_bounds__(256, 3) void msg_fused_kernel(
    const unsigned short* __restrict__ nodeB, const i32x4* __restrict__ meta,
    const float* __restrict__ edge_emb, const unsigned short* __restrict__ WtM,
    const float* __restrict__ b_msg, const int* __restrict__ base,
    const int* __restrict__ cnt, unsigned int* __restrict__ meanB32,
    float* __restrict__ spill)
{
    __shared__ unsigned short sIn[TILE][192];    // 24576 B; 16B chunks XOR row&7
    __shared__ unsigned short sMsg[TILE][128];   // 16384 B; 8B chunks XOR row&7

    const int lane = threadIdx.x & 63;
    const int wav  = threadIdx.x >> 6;
    const int j = lane & 15;
    const int q = lane >> 4;

    // W slice (out rows 32*wav .. 32*wav+31) in registers
    frag8 wfr[2][6];
#pragma unroll
    for (int m2 = 0; m2 < 2; ++m2) {
        const unsigned short* wrow = WtM + ((wav * 2 + m2) * 16 + j) * K1;
#pragma unroll
        for (int kc = 0; kc < 6; ++kc)
            wfr[m2][kc] = *(const frag8*)&wrow[(kc * 4 + q) * 8];
    }
    float bias[2][4];
#pragma unroll
    for (int m2 = 0; m2 < 2; ++m2)
#pragma unroll
        for (int r = 0; r < 4; ++r) bias[m2][r] = b_msg[(wav * 2 + m2) * 16 + q * 4 + r];

    // staging role: thread t covers edge row eL = t>>2, quarter qt = t&3
    const int eL = threadIdx.x >> 2;
    const int qt = threadIdx.x & 3;
    const int swz = eL & 7;

    uint4 nst[4];    // node part: 64B bf16 (cached path)
    f32x4 est[4];    // edge part: 64B f32 (non-temporal streaming)

    const int t0 = blockIdx.x;

    // prologue: issue loads for tile t0
    {
        const int e = t0 * TILE + eL;
        const i32x4 m = __builtin_nontemporal_load(&meta[e]);
        const int sp = min(max(m[1], 0), N_NODES - 1);
        const unsigned short* nrow = nodeB + (size_t)sp * D_NODE + qt * 32;
#pragma unroll
        for (int i = 0; i < 4; ++i) nst[i] = *(const uint4*)&nrow[i * 8];
        const float* erow = edge_emb + (size_t)m[0] * D_EDGE + qt * 16;
#pragma unroll
        for (int i = 0; i < 4; ++i)
            est[i] = __builtin_nontemporal_load((const f32x4*)&erow[i * 4]);
    }

#pragma unroll 1
    for (int t = t0; t < NT; t += gridDim.x) {
        const int e0 = t * TILE;

        __syncthreads();   // (a) prior GEMM + reduction done; sIn free

        // write staged tile into sIn (XOR-swizzled 16B chunks)
        {
            unsigned short* drow = &sIn[eL][0];
#pragma unroll
            for (int i = 0; i < 4; ++i)
                *(uint4*)&drow[((4 * qt + i) ^ swz) * 8] = nst[i];
#pragma unroll
            for (int h = 0; h < 2; ++h) {
                F8 u;
                u.f = pack8v(est[h * 2], est[h * 2 + 1]);
                *(uint4*)&drow[((16 + 2 * qt + h) ^ swz) * 8] = u.u4;
            }
        }
        __syncthreads();   // (b) sIn ready

        // issue next tile's loads early (latency hides under compute)
        const int tn = t + gridDim.x;
        if (tn < NT) {
            const int e = tn * TILE + eL;
            const i32x4 m = __builtin_nontemporal_load(&meta[e]);
            const int sp = min(max(m[1], 0), N_NODES - 1);
            const unsigned short* nrow = nodeB + (size_t)sp * D_NODE + qt * 32;
#pragma unroll
            for (int i = 0; i < 4; ++i) nst[i] = *(const uint4*)&nrow[i * 8];
            const float* erow = edge_emb + (size_t)m[0] * D_EDGE + qt * 16;
#pragma unroll
            for (int i = 0; i < 4; ++i)
                est[i] = __builtin_nontemporal_load((const f32x4*)&erow[i * 4]);
        }

        // GEMM: wave computes outs 32*wav..+31 for all 64 edges
        facc acc[2][4];
#pragma unroll
        for (int m2 = 0; m2 < 2; ++m2)
#pragma unroll
            for (int eg = 0; eg < 4; ++eg) { facc z = {0.f,0.f,0.f,0.f}; acc[m2][eg] = z; }

        const int rsw = j & 7;
#pragma unroll
        for (int eg = 0; eg < 4; ++eg) {
            const unsigned short* irow = &sIn[eg * 16 + j][0];
#pragma unroll
            for (int kc = 0; kc < 6; ++kc) {
                frag8 b = *(const frag8*)&irow[((4 * kc + q) ^ rsw) * 8];
                acc[0][eg] = __builtin_amdgcn_mfma_f32_16x16x32_bf16(wfr[0][kc], b, acc[0][eg], 0, 0, 0);
                acc[1][eg] = __builtin_amdgcn_mfma_f32_16x16x32_bf16(wfr[1][kc], b, acc[1][eg], 0, 0, 0);
            }
        }

        // epilogue: bias+relu+cvt bf16 -> sMsg (8B chunks XOR row&7)
#pragma unroll
        for (int eg = 0; eg < 4; ++eg) {
            unsigned short* mrow = &sMsg[eg * 16 + j][0];
#pragma unroll
            for (int m2 = 0; m2 < 2; ++m2) {
                float v0 = fmaxf(acc[m2][eg][0] + bias[m2][0], 0.f);
                float v1 = fmaxf(acc[m2][eg][1] + bias[m2][1], 0.f);
                float v2 = fmaxf(acc[m2][eg][2] + bias[m2][2], 0.f);
                float v3 = fmaxf(acc[m2][eg][3] + bias[m2][3], 0.f);
                uint2 w;
                w.x = (unsigned)f2bf(v0) | ((unsigned)f2bf(v1) << 16);
                w.y = (unsigned)f2bf(v2) | ((unsigned)f2bf(v3) << 16);
                int c64 = wav * 8 + m2 * 4 + q;        // u64 index 0..31
                *(uint2*)&mrow[(c64 ^ rsw) * 4] = w;
            }
        }
        __syncthreads();   // (c) sMsg ready

        // in-block mean finish: wave handles nodes d_lo+wav, +4, ...
        const int d_lo = meta[e0][2];
        const int d_hi = meta[e0 + TILE - 1][2];
        for (int n = d_lo + wav; n <= d_hi; n += 4) {
            const int b = base[n];
            const int c = cnt[n];
            const int lo = max(b - e0, 0);
            const int hi = min(b + c - e0, TILE);
            float s0 = 0.f, s1 = 0.f;
            for (int r = lo; r < hi; ++r) {
                const unsigned* mr = (const unsigned*)&sMsg[r][0];
                unsigned u = mr[(((lane >> 1) ^ (r & 7)) << 1) | (lane & 1)];
                s0 += bflo(u); s1 += bfhi(u);
            }
            const float inv = 1.0f / fmaxf((float)c, 1.0f);
            s0 *= inv; s1 *= inv;
            if (b >= e0 && b + c <= e0 + TILE) {
                // interior: exclusive owner, direct bf16 mean row write (nt)
                unsigned int w = (unsigned)f2bf(s0) | ((unsigned)f2bf(s1) << 16);
                __builtin_nontemporal_store(w, &meanB32[(size_t)n * 64 + lane]);
            } else {
                // non-interior: deterministic f32 spill slot (NO atomics, nt)
                int slot = (n == d_lo) ? 0 : 1;
                f32x2 w; w[0] = s0; w[1] = s1;
                __builtin_nontemporal_store(
                    w, (f32x2*)(spill + ((size_t)(t * 2 + slot)) * D_MSG + lane * 2));
            }
        }
    }
}

// ---------------------------------------------------------------------------
// cleanup: finish boundary nodes (sum their per-tile spill rows) and write
// zero rows for degree-0 nodes. Interior nodes were written by msg_fused.
// ---------------------------------------------------------------------------
__global__ __launch_bounds__(256) void cleanup_kernel(
    const i32x4* __restrict__ meta, const int* __restrict__ base,
    const int* __restrict__ cnt, const float* __restrict__ spill,
    unsigned int* __restrict__ meanB32)
{
    const int wav = threadIdx.x >> 6;
    const int lane = threadIdx.x & 63;
    const int n = blockIdx.x * 4 + wav;
    const int c = cnt[n];
    float s0 = 0.f, s1 = 0.f;
    if (c > 0) {
        const int b = base[n];
        const int t0 = b >> 6, t1 = (b + c - 1) >> 6;
        if (t0 == t1) return;   // interior: already written by msg_fused
        for (int t = t0; t <= t1; ++t) {
            const int slot = (meta[t * TILE][2] == n) ? 0 : 1;
            const float* sp = spill + ((size_t)(t * 2 + slot)) * D_MSG + lane * 2;
            s0 += sp[0]; s1 += sp[1];
        }
    }
    meanB32[(size_t)n * 64 + lane] = (unsigned)f2bf(s0) | ((unsigned)f2bf(s1) << 16);
}

// ---------------------------------------------------------------------------
// Phase C: node GEMM, all-bf16 fragment loads (nodeB + meanB).
// ---------------------------------------------------------------------------
__global__ __launch_bounds__(256) void node_gemm_kernel(
    const unsigned short* __restrict__ nodeB, const unsigned short* __restrict__ meanB,
    const unsigned short* __restrict__ WtU, const float* __restrict__ b_upd,
    float* __restrict__ out)
{
    __shared__ unsigned short sW[128 * K2];   // 65536 B

    for (int idx = threadIdx.x; idx < 128 * 32; idx += 256) {
        int o = idx >> 5, ch = idx & 31;
        *(uint4*)&sW[o * K2 + (ch ^ (o & 7)) * 8] = *(const uint4*)&WtU[o * K2 + ch * 8];
    }

    const int lane = threadIdx.x & 63;
    const int wav  = threadIdx.x >> 6;
    const int j = lane & 15;
    const int q = lane >> 4;
    const int rs = j & 7;

    float bias[32];
#pragma unroll
    for (int mt = 0; mt < 8; ++mt)
#pragma unroll
        for (int r = 0; r < 4; ++r) bias[mt * 4 + r] = b_upd[mt * 16 + q * 4 + r];
    __syncthreads();

    const int n0w = blockIdx.x * 256 + wav * 64;

#pragma unroll 1
    for (int g = 0; g < 4; ++g) {
        const int n = n0w + g * 16 + j;
        const bool valid = (n < N_NODES);
        const size_t nn = valid ? (size_t)n : 0;

        frag8 bfr[8];
        const unsigned short* nrow = nodeB + nn * D_NODE;
#pragma unroll
        for (int kc = 0; kc < 4; ++kc)
            bfr[kc] = *(const frag8*)&nrow[kc * 32 + q * 8];
        const unsigned short* mrow = meanB + nn * D_MSG;
#pragma unroll
        for (int kc = 0; kc < 4; ++kc)
            bfr[4 + kc] = *(const frag8*)&mrow[kc * 32 + q * 8];

        facc acc[8];
#pragma unroll
        for (int mt = 0; mt < 8; ++mt) { facc z = {0.f, 0.f, 0.f, 0.f}; acc[mt] = z; }

#pragma unroll
        for (int mt = 0; mt < 8; ++mt) {
            const unsigned short* wrow = &sW[(mt * 16 + j) * K2];
#pragma unroll
            for (int kc = 0; kc < 8; ++kc) {
                frag8 a = *(const frag8*)&wrow[((kc * 4 + q) ^ rs) * 8];
                acc[mt] = __builtin_amdgcn_mfma_f32_16x16x32_bf16(a, bfr[kc], acc[mt], 0, 0, 0);
            }
        }

        if (valid) {
            float* orow = out + (size_t)n * D_OUT;
#pragma unroll
            for (int mt = 0; mt < 8; ++mt)
#pragma unroll
                for (int r = 0; r < 4; ++r)
                    orow[mt * 16 + q * 4 + r] = fmaxf(acc[mt][r] + bias[mt * 4 + r], 0.f);
        }
    }
}

// ===========================================================================
// FALLBACK PATH (round-3 style, meta-packed): fused msg+aggregate if ws small.
// ===========================================================================
__global__ void prep_w_kernel(const float* __restrict__ Wm, const float* __restrict__ Wu,
                              unsigned short* __restrict__ WtM, unsigned short* __restrict__ WtU) {
    int idx0 = blockIdx.x * blockDim.x + threadIdx.x;
    int stride = gridDim.x * blockDim.x;
    for (int idx = idx0; idx < 128 * K1; idx += stride) {
        int o = idx / K1, k = idx - o * K1;
        WtM[idx] = f2bf(Wm[k * D_MSG + o]);
    }
    for (int idx = idx0; idx < 128 * K2; idx += stride) {
        int o = idx >> 8, k = idx & 255;
        WtU[idx] = f2bf(Wu[k * D_OUT + o]);
    }
}

__global__ void hist_kernel(const int* __restrict__ dst, int* __restrict__ cnt) {
    int idx0 = blockIdx.x * blockDim.x + threadIdx.x;
    int stride = gridDim.x * blockDim.x;
    for (int e = idx0; e < N_EDGES; e += stride) {
        int d = min(max(dst[e], 0), N_NODES - 1);
        atomicAdd(&cnt[d], 1);
    }
}

__global__ __launch_bounds__(256) void msg_agg_kernel_fb(
    const float* __restrict__ node_emb, const i32x4* __restrict__ meta,
    const float* __restrict__ edge_emb, const unsigned short* __restrict__ WtM,
    const float* __restrict__ b_msg, const int* __restrict__ cnt,
    float* __restrict__ mean)
{
    __shared__ unsigned short sW[128 * K1];

    for (int idx = threadIdx.x; idx < 128 * 24; idx += 256) {
        int o = idx / 24, ch = idx % 24;
        *(uint4*)&sW[o * K1 + (ch ^ (o & 7)) * 8] = *(const uint4*)&WtM[o * K1 + ch * 8];
    }

    const int lane = threadIdx.x & 63;
    const int wav  = threadIdx.x >> 6;
    const int j = lane & 15;
    const int q = lane >> 4;

    float bias[32];
#pragma unroll
    for (int mt = 0; mt < 8; ++mt)
#pragma unroll
        for (int r = 0; r < 4; ++r) bias[mt * 4 + r] = b_msg[mt * 16 + q * 4 + r];
    __syncthreads();

    const int e0w = blockIdx.x * 256 + wav * 64;
    float carry[32];
    int carry_d = -1;

#pragma unroll 1
    for (int g = 0; g < 4; ++g) {
        const int e = e0w + g * 16 + j;
        const i32x4 m = meta[e];
        const int p = m[0];
        const int d = m[2];
        const int sp = min(max(m[1], 0), N_NODES - 1);
        const float invc = 1.0f / (float)cnt[d];

        frag8 bfr[6];
        const float* nrow = node_emb + (size_t)sp * D_NODE;
#pragma unroll
        for (int kc = 0; kc < 4; ++kc) {
            float4 a = *(const float4*)&nrow[kc * 32 + q * 8];
            float4 c = *(const float4*)&nrow[kc * 32 + q * 8 + 4];
            bfr[kc] = pack8(a, c);
        }
        const float* erow = edge_emb + (size_t)p * D_EDGE;
#pragma unroll
        for (int kc = 0; kc < 2; ++kc) {
            float4 a = *(const float4*)&erow[kc * 32 + q * 8];
            float4 c = *(const float4*)&erow[kc * 32 + q * 8 + 4];
            bfr[4 + kc] = pack8(a, c);
        }

        facc acc[8];
#pragma unroll
        for (int mt = 0; mt < 8; ++mt) { facc z = {0.f, 0.f, 0.f, 0.f}; acc[mt] = z; }

#pragma unroll
        for (int mt = 0; mt < 8; ++mt) {
            const unsigned short* wrow = &sW[(mt * 16 + j) * K1];
            const int rs = j & 7;
#pragma unroll
            for (int kc = 0; kc < 6; ++kc) {
                frag8 a = *(const frag8*)&wrow[((kc * 4 + q) ^ rs) * 8];
                acc[mt] = __builtin_amdgcn_mfma_f32_16x16x32_bf16(a, bfr[kc], acc[mt], 0, 0, 0);
            }
        }

        float v[32];
#pragma unroll
        for (int mt = 0; mt < 8; ++mt)
#pragma unroll
            for (int r = 0; r < 4; ++r) {
                float t = acc[mt][r] + bias[mt * 4 + r];
                v[mt * 4 + r] = fmaxf(t, 0.f) * invc;
            }

        int dprev = __shfl_up(d, 1, 16);
        int head = (j == 0 || d != dprev) ? 1 : 0;
        int seg = head;
#pragma unroll
        for (int s = 1; s < 16; s <<= 1) { int t = __shfl_up(seg, s, 16); if (j >= s) seg += t; }
        int sg1 = __shfl_up(seg, 1, 16);
        int sg2 = __shfl_up(seg, 2, 16);
        int sg4 = __shfl_up(seg, 4, 16);
        int sg8 = __shfl_up(seg, 8, 16);
        bool ok1 = (j >= 1) && (sg1 == seg);
        bool ok2 = (j >= 2) && (sg2 == seg);
        bool ok4 = (j >= 4) && (sg4 == seg);
        bool ok8 = (j >= 8) && (sg8 == seg);

#pragma unroll
        for (int i = 0; i < 32; ++i) { float t = __shfl_up(v[i], 1, 16); if (ok1) v[i] += t; }
#pragma unroll
        for (int i = 0; i < 32; ++i) { float t = __shfl_up(v[i], 2, 16); if (ok2) v[i] += t; }
#pragma unroll
        for (int i = 0; i < 32; ++i) { float t = __shfl_up(v[i], 4, 16); if (ok4) v[i] += t; }
#pragma unroll
        for (int i = 0; i < 32; ++i) { float t = __shfl_up(v[i], 8, 16); if (ok8) v[i] += t; }

        int d0 = __shfl(d, 0, 16);
        if (g > 0) {
            if (d0 != carry_d) {
                if (j == 0) {
                    float* mrow = mean + (size_t)carry_d * D_MSG;
#pragma unroll
                    for (int mt = 0; mt < 8; ++mt)
#pragma unroll
                        for (int r = 0; r < 4; ++r)
                            atomicAdd(&mrow[mt * 16 + q * 4 + r], carry[mt * 4 + r]);
                }
            } else if (seg == 1) {
#pragma unroll
                for (int i = 0; i < 32; ++i) v[i] += carry[i];
            }
        }

#pragma unroll
        for (int i = 0; i < 32; ++i) carry[i] = __shfl(v[i], 15, 16);
        carry_d = __shfl(d, 15, 16);

        int dnext = __shfl_down(d, 1, 16);
        bool tail = (j < 15) ? (dnext != d) : (g == 3);
        if (tail) {
            float* mrow = mean + (size_t)d * D_MSG;
#pragma unroll
            for (int mt = 0; mt < 8; ++mt)
#pragma unroll
                for (int r = 0; r < 4; ++r)
                    atomicAdd(&mrow[mt * 16 + q * 4 + r], v[mt * 4 + r]);
        }
    }
}

__global__ __launch_bounds__(256) void node_kernel_fb(
    const float* __restrict__ node_emb, const float* __restrict__ mean,
    const unsigned short* __restrict__ WtU, const float* __restrict__ b_upd,
    float* __restrict__ out)
{
    __shared__ unsigned short sW[128 * K2];

    for (int idx = threadIdx.x; idx < 128 * 32; idx += 256) {
        int o = idx >> 5, ch = idx & 31;
        *(uint4*)&sW[o * K2 + (ch ^ (o & 7)) * 8] = *(const uint4*)&WtU[o * K2 + ch * 8];
    }

    const int lane = threadIdx.x & 63;
    const int wav  = threadIdx.x >> 6;
    const int j = lane & 15;
    const int q = lane >> 4;

    float bias[32];
#pragma unroll
    for (int mt = 0; mt < 8; ++mt)
#pragma unroll
        for (int r = 0; r < 4; ++r) bias[mt * 4 + r] = b_upd[mt * 16 + q * 4 + r];
    __syncthreads();

    const int n0w = blockIdx.x * 256 + wav * 64;

#pragma unroll 1
    for (int g = 0; g < 4; ++g) {
        const int n = n0w + g * 16 + j;
        const bool valid = (n < N_NODES);
        const size_t nn = valid ? (size_t)n : 0;

        frag8 bfr[8];
        const float* nrow = node_emb + nn * D_NODE;
#pragma unroll
        for (int kc = 0; kc < 4; ++kc) {
            float4 a = *(const float4*)&nrow[kc * 32 + q * 8];
            float4 c = *(const float4*)&nrow[kc * 32 + q * 8 + 4];
            bfr[kc] = pack8(a, c);
        }
        const float* mrow = mean + nn * D_MSG;
#pragma unroll
        for (int kc = 0; kc < 4; ++kc) {
            float4 a = *(const float4*)&mrow[kc * 32 + q * 8];
            float4 c = *(const float4*)&mrow[kc * 32 + q * 8 + 4];
            bfr[4 + kc] = pack8(a, c);
        }

        facc acc[8];
#pragma unroll
        for (int mt = 0; mt < 8; ++mt) { facc z = {0.f, 0.f, 0.f, 0.f}; acc[mt] = z; }

#pragma unroll
        for (int mt = 0; mt < 8; ++mt) {
            const unsigned short* wrow = &sW[(mt * 16 + j) * K2];
            const int rs = j & 7;
#pragma unroll
            for (int kc = 0; kc < 8; ++kc) {
                frag8 a = *(const frag8*)&wrow[((kc * 4 + q) ^ rs) * 8];
                acc[mt] = __builtin_amdgcn_mfma_f32_16x16x32_bf16(a, bfr[kc], acc[mt], 0, 0, 0);
            }
        }

        if (valid) {
            float* orow = out + (size_t)n * D_OUT;
#pragma unroll
            for (int mt = 0; mt < 8; ++mt)
#pragma unroll
                for (int r = 0; r < 4; ++r)
                    orow[mt * 16 + q * 4 + r] = fmaxf(acc[mt][r] + bias[mt * 4 + r], 0.f);
        }
    }
}

extern "C" void kernel_launch(void* const* d_in, const int* in_sizes, int n_in,
                              void* d_out, int out_size, void* d_ws, size_t ws_size,
                              hipStream_t stream) {
    const float* node_emb = (const float*)d_in[0];
    const int*   edge_idx = (const int*)d_in[1];
    const float* edge_emb = (const float*)d_in[2];
    const float* W_msg    = (const float*)d_in[3];
    const float* b_msg    = (const float*)d_in[4];
    const float* W_upd    = (const float*)d_in[5];
    const float* b_upd    = (const float*)d_in[6];
    float* out = (float*)d_out;

    const int* src = edge_idx;
    const int* dst = edge_idx + N_EDGES;

    char* W = (char*)d_ws;

    if (ws_size >= 104000000ULL) {
        // ---- FAST PATH ----
        unsigned short* meanB = (unsigned short*)(W + 0);         // 25,600,000
        int* cnt     = (int*)(W + 25600000);                      //    400,000
        int* cursor  = (int*)(W + 26000000);                      //    400,000
        int* base    = (int*)(W + 26400000);                      //    400,000
        int* part    = (int*)(W + 26800000);                      //        512
        i32x4* meta  = (i32x4*)(W + 26800512);                    // 25,600,000
        unsigned short* WtM   = (unsigned short*)(W + 52400512);  //     49,152
        unsigned short* WtU   = (unsigned short*)(W + 52449664);  //     65,536
        unsigned short* nodeB = (unsigned short*)(W + 52515200);  // 25,600,000
        float* spill = (float*)(W + 78115200);                    //  25,600,000

        // zero only cnt + cursor
        hipMemsetAsync(W + 25600000, 0, 800000, stream);

        prep_all_kernel<<<2048, 256, 0, stream>>>(W_msg, W_upd, node_emb, dst,
                                                  WtM, WtU, (unsigned int*)nodeB, cnt);
        scan_blocks<<<NSB, 1024, 0, stream>>>(cnt, base, part);
        scan_add<<<NSB, 1024, 0, stream>>>(base, part);
        scatter_kernel<<<1024, 256, 0, stream>>>(dst, src, base, cursor, meta);
        msg_fused_kernel<<<2048, 256, 0, stream>>>(nodeB, meta, edge_emb,
                                                   WtM, b_msg, base, cnt,
                                                   (unsigned int*)meanB, spill);
        cleanup_kernel<<<25000, 256, 0, stream>>>(meta, base, cnt, spill,
                                                  (unsigned int*)meanB);
        node_gemm_kernel<<<391, 256, 0, stream>>>(nodeB, meanB, WtU, b_upd, out);
    } else {
        // ---- FALLBACK ----
        float* mean  = (float*)W;                               // 51,200,000
        int* cnt     = (int*)(W + 51200000);
        int* cursor  = (int*)(W + 51600000);
        int* base    = (int*)(W + 52000000);
        int* part    = (int*)(W + 52400000);
        i32x4* meta  = (i32x4*)(W + 52400512);                  // 25,600,000
        unsigned short* WtM = (unsigned short*)(W + 78000512);
        unsigned short* WtU = (unsigned short*)(W + 78049664);

        hipMemsetAsync(d_ws, 0, 52000000, stream);

        prep_w_kernel<<<224, 256, 0, stream>>>(W_msg, W_upd, WtM, WtU);
        hist_kernel<<<1024, 256, 0, stream>>>(dst, cnt);
        scan_blocks<<<NSB, 1024, 0, stream>>>(cnt, base, part);
        scan_add<<<NSB, 1024, 0, stream>>>(base, part);
        scatter_kernel<<<1024, 256, 0, stream>>>(dst, src, base, cursor, meta);
        msg_agg_kernel_fb<<<6250, 256, 0, stream>>>(node_emb, meta, edge_emb, WtM,
                                                    b_msg, cnt, mean);
        node_kernel_fb<<<391, 256, 0, stream>>>(node_emb, mean, WtU, b_upd, out);
    }
}

// Round 11
// 588.783 us; speedup vs baseline: 1.0533x; 1.0533x over previous
//
#include <hip/hip_runtime.h>
#include <hip/hip_bf16.h>

#define N_NODES 100000
#define N_EDGES 1600000
#define D_NODE 128
#define D_EDGE 64
#define D_MSG 128
#define K1 192   // NODE_DIM + EDGE_DIM
#define K2 256   // NODE_DIM + MSG_DIM
#define D_OUT 128
#define NSB 98   // scan blocks: ceil(100000/1024)
#define TILE 64
#define NT (N_EDGES / TILE)   // 25000 exact

using frag8 = __attribute__((ext_vector_type(8))) short;   // 8 bf16 (4 VGPRs)
using facc  = __attribute__((ext_vector_type(4))) float;   // 4 f32 acc
typedef int   i32x4 __attribute__((ext_vector_type(4)));
typedef float f32x2 __attribute__((ext_vector_type(2)));

static __device__ __forceinline__ unsigned short f2bf(float f) {
    unsigned int u = __float_as_uint(f);
    u = u + 0x7fffu + ((u >> 16) & 1u);   // RNE
    return (unsigned short)(u >> 16);
}
static __device__ __forceinline__ float bflo(unsigned int u) { return __uint_as_float(u << 16); }
static __device__ __forceinline__ float bfhi(unsigned int u) { return __uint_as_float(u & 0xffff0000u); }

union F8 { unsigned short s[8]; frag8 f; uint4 u4; };

static __device__ __forceinline__ frag8 pack8(float4 a, float4 b) {
    F8 u;
    u.s[0] = f2bf(a.x); u.s[1] = f2bf(a.y); u.s[2] = f2bf(a.z); u.s[3] = f2bf(a.w);
    u.s[4] = f2bf(b.x); u.s[5] = f2bf(b.y); u.s[6] = f2bf(b.z); u.s[7] = f2bf(b.w);
    return u.f;
}

// ---------------------------------------------------------------------------
// prep_all: W transpose->bf16, node_emb->bf16, dst histogram. One launch.
// ---------------------------------------------------------------------------
__global__ void prep_all_kernel(const float* __restrict__ Wm, const float* __restrict__ Wu,
                                const float* __restrict__ node_emb, const int* __restrict__ dst,
                                unsigned short* __restrict__ WtM, unsigned short* __restrict__ WtU,
                                unsigned int* __restrict__ nodeB32, int* __restrict__ cnt) {
    int idx0 = blockIdx.x * blockDim.x + threadIdx.x;
    int stride = gridDim.x * blockDim.x;
    for (int idx = idx0; idx < 128 * K1; idx += stride) {
        int o = idx / K1, k = idx - o * K1;
        WtM[idx] = f2bf(Wm[k * D_MSG + o]);
    }
    for (int idx = idx0; idx < 128 * K2; idx += stride) {
        int o = idx >> 8, k = idx & 255;
        WtU[idx] = f2bf(Wu[k * D_OUT + o]);
    }
    const int total = N_NODES * 64;   // u32 pairs
    for (int i = idx0; i < total; i += stride) {
        float2 v = *(const float2*)&node_emb[(size_t)i * 2];
        nodeB32[i] = (unsigned)f2bf(v.x) | ((unsigned)f2bf(v.y) << 16);
    }
    for (int e = idx0; e < N_EDGES; e += stride) {
        int d = min(max(dst[e], 0), N_NODES - 1);
        atomicAdd(&cnt[d], 1);
    }
}

__global__ __launch_bounds__(1024) void scan_blocks(const int* __restrict__ cnt,
                                                    int* __restrict__ base,
                                                    int* __restrict__ part) {
    __shared__ int sh[1024];
    int i = blockIdx.x * 1024 + threadIdx.x;
    int c = (i < N_NODES) ? cnt[i] : 0;
    sh[threadIdx.x] = c;
    __syncthreads();
    for (int s = 1; s < 1024; s <<= 1) {
        int t = (threadIdx.x >= s) ? sh[threadIdx.x - s] : 0;
        __syncthreads();
        sh[threadIdx.x] += t;
        __syncthreads();
    }
    if (i < N_NODES) base[i] = sh[threadIdx.x] - c;   // exclusive within block
    if (threadIdx.x == 1023) part[blockIdx.x] = sh[1023];   // raw block sum
}

// scan_add: computes this block's partial-prefix in-wave (no scan_partials pass)
__global__ __launch_bounds__(1024) void scan_add(int* __restrict__ base, const int* __restrict__ part) {
    __shared__ int soff;
    if (threadIdx.x < 64) {
        int l = threadIdx.x;
        int v = 0;
        if (l < blockIdx.x) v += part[l];
        if (l + 64 < blockIdx.x) v += part[l + 64];
#pragma unroll
        for (int s = 32; s; s >>= 1) v += __shfl_down(v, s, 64);
        if (l == 0) soff = v;
    }
    __syncthreads();
    int i = blockIdx.x * 1024 + threadIdx.x;
    if (i < N_NODES) base[i] += soff;
}

// ---------------------------------------------------------------------------
// scatter: bins edges by dst; ONE packed int4 nt-store per edge
// meta[pos] = {orig_e, src[e], d, 0}
// ---------------------------------------------------------------------------
__global__ void scatter_kernel(const int* __restrict__ dst, const int* __restrict__ src,
                               const int* __restrict__ base, int* __restrict__ cursor,
                               i32x4* __restrict__ meta) {
    int idx0 = blockIdx.x * blockDim.x + threadIdx.x;
    int stride = gridDim.x * blockDim.x;
    for (int e = idx0; e < N_EDGES; e += stride) {
        int d = min(max(dst[e], 0), N_NODES - 1);
        int pos = base[d] + atomicAdd(&cursor[d], 1);
        i32x4 m; m[0] = e; m[1] = src[e]; m[2] = d; m[3] = 0;
        __builtin_nontemporal_store(m, &meta[pos]);
    }
}

// ---------------------------------------------------------------------------
// FUSED Phase A: per 64-edge tile: msg GEMM (W in regs, inputs staged in
// XOR-swizzled LDS) -> msg tile in LDS -> in-block per-node mean.
// CACHED loads (r9 — latency path needs L2); NON-TEMPORAL stores only
// (r10 — cuts WRITE without touching load latency).
// ---------------------------------------------------------------------------
__global__ __launch_bounds__(256, 4) void msg_fused_kernel(
    const unsigned short* __restrict__ nodeB, const i32x4* __restrict__ meta,
    const float* __restrict__ edge_emb, const unsigned short* __restrict__ WtM,
    const float* __restrict__ b_msg, const int* __restrict__ base,
    const int* __restrict__ cnt, unsigned int* __restrict__ meanB32,
    float* __restrict__ spill)
{
    __shared__ unsigned short sIn[TILE][192];    // 24576 B; 16B chunks XOR row&7
    __shared__ unsigned short sMsg[TILE][128];   // 16384 B; 8B chunks XOR row&7

    const int lane = threadIdx.x & 63;
    const int wav  = threadIdx.x >> 6;
    const int j = lane & 15;
    const int q = lane >> 4;

    // W slice (out rows 32*wav .. 32*wav+31) in registers
    frag8 wfr[2][6];
#pragma unroll
    for (int m2 = 0; m2 < 2; ++m2) {
        const unsigned short* wrow = WtM + ((wav * 2 + m2) * 16 + j) * K1;
#pragma unroll
        for (int kc = 0; kc < 6; ++kc)
            wfr[m2][kc] = *(const frag8*)&wrow[(kc * 4 + q) * 8];
    }
    float bias[2][4];
#pragma unroll
    for (int m2 = 0; m2 < 2; ++m2)
#pragma unroll
        for (int r = 0; r < 4; ++r) bias[m2][r] = b_msg[(wav * 2 + m2) * 16 + q * 4 + r];

    // staging role: thread t covers edge row eL = t>>2, quarter qt = t&3
    const int eL = threadIdx.x >> 2;
    const int qt = threadIdx.x & 3;
    const int swz = eL & 7;

    uint4  nst[4];    // node part: 64B bf16 (cached gather)
    float4 est[4];    // edge part: 64B f32 (cached)

    const int t0 = blockIdx.x;

    // prologue: issue loads for tile t0
    {
        const int e = t0 * TILE + eL;
        const i32x4 m = meta[e];
        const int sp = min(max(m[1], 0), N_NODES - 1);
        const unsigned short* nrow = nodeB + (size_t)sp * D_NODE + qt * 32;
#pragma unroll
        for (int i = 0; i < 4; ++i) nst[i] = *(const uint4*)&nrow[i * 8];
        const float* erow = edge_emb + (size_t)m[0] * D_EDGE + qt * 16;
#pragma unroll
        for (int i = 0; i < 4; ++i) est[i] = *(const float4*)&erow[i * 4];
    }

#pragma unroll 1
    for (int t = t0; t < NT; t += gridDim.x) {
        const int e0 = t * TILE;

        __syncthreads();   // (a) prior GEMM + reduction done; sIn free

        // write staged tile into sIn (XOR-swizzled 16B chunks)
        {
            unsigned short* drow = &sIn[eL][0];
#pragma unroll
            for (int i = 0; i < 4; ++i)
                *(uint4*)&drow[((4 * qt + i) ^ swz) * 8] = nst[i];
#pragma unroll
            for (int h = 0; h < 2; ++h) {
                F8 u;
                u.f = pack8(est[h * 2], est[h * 2 + 1]);
                *(uint4*)&drow[((16 + 2 * qt + h) ^ swz) * 8] = u.u4;
            }
        }
        __syncthreads();   // (b) sIn ready

        // issue next tile's loads early (latency hides under compute)
        const int tn = t + gridDim.x;
        if (tn < NT) {
            const int e = tn * TILE + eL;
            const i32x4 m = meta[e];
            const int sp = min(max(m[1], 0), N_NODES - 1);
            const unsigned short* nrow = nodeB + (size_t)sp * D_NODE + qt * 32;
#pragma unroll
            for (int i = 0; i < 4; ++i) nst[i] = *(const uint4*)&nrow[i * 8];
            const float* erow = edge_emb + (size_t)m[0] * D_EDGE + qt * 16;
#pragma unroll
            for (int i = 0; i < 4; ++i) est[i] = *(const float4*)&erow[i * 4];
        }

        // GEMM: wave computes outs 32*wav..+31 for all 64 edges
        facc acc[2][4];
#pragma unroll
        for (int m2 = 0; m2 < 2; ++m2)
#pragma unroll
            for (int eg = 0; eg < 4; ++eg) { facc z = {0.f,0.f,0.f,0.f}; acc[m2][eg] = z; }

        const int rsw = j & 7;
#pragma unroll
        for (int eg = 0; eg < 4; ++eg) {
            const unsigned short* irow = &sIn[eg * 16 + j][0];
#pragma unroll
            for (int kc = 0; kc < 6; ++kc) {
                frag8 b = *(const frag8*)&irow[((4 * kc + q) ^ rsw) * 8];
                acc[0][eg] = __builtin_amdgcn_mfma_f32_16x16x32_bf16(wfr[0][kc], b, acc[0][eg], 0, 0, 0);
                acc[1][eg] = __builtin_amdgcn_mfma_f32_16x16x32_bf16(wfr[1][kc], b, acc[1][eg], 0, 0, 0);
            }
        }

        // epilogue: bias+relu+cvt bf16 -> sMsg (8B chunks XOR row&7)
#pragma unroll
        for (int eg = 0; eg < 4; ++eg) {
            unsigned short* mrow = &sMsg[eg * 16 + j][0];
#pragma unroll
            for (int m2 = 0; m2 < 2; ++m2) {
                float v0 = fmaxf(acc[m2][eg][0] + bias[m2][0], 0.f);
                float v1 = fmaxf(acc[m2][eg][1] + bias[m2][1], 0.f);
                float v2 = fmaxf(acc[m2][eg][2] + bias[m2][2], 0.f);
                float v3 = fmaxf(acc[m2][eg][3] + bias[m2][3], 0.f);
                uint2 w;
                w.x = (unsigned)f2bf(v0) | ((unsigned)f2bf(v1) << 16);
                w.y = (unsigned)f2bf(v2) | ((unsigned)f2bf(v3) << 16);
                int c64 = wav * 8 + m2 * 4 + q;        // u64 index 0..31
                *(uint2*)&mrow[(c64 ^ rsw) * 4] = w;
            }
        }
        __syncthreads();   // (c) sMsg ready

        // in-block mean finish: wave handles nodes d_lo+wav, +4, ...
        const int d_lo = ((const int*)&meta[e0])[2];
        const int d_hi = ((const int*)&meta[e0 + TILE - 1])[2];
        for (int n = d_lo + wav; n <= d_hi; n += 4) {
            const int b = base[n];
            const int c = cnt[n];
            const int lo = max(b - e0, 0);
            const int hi = min(b + c - e0, TILE);
            float s0 = 0.f, s1 = 0.f;
            for (int r = lo; r < hi; ++r) {
                const unsigned* mr = (const unsigned*)&sMsg[r][0];
                unsigned u = mr[(((lane >> 1) ^ (r & 7)) << 1) | (lane & 1)];
                s0 += bflo(u); s1 += bfhi(u);
            }
            const float inv = 1.0f / fmaxf((float)c, 1.0f);
            s0 *= inv; s1 *= inv;
            if (b >= e0 && b + c <= e0 + TILE) {
                // interior: exclusive owner, direct bf16 mean row write (nt)
                unsigned int w = (unsigned)f2bf(s0) | ((unsigned)f2bf(s1) << 16);
                __builtin_nontemporal_store(w, &meanB32[(size_t)n * 64 + lane]);
            } else {
                // non-interior: deterministic f32 spill slot (NO atomics, nt)
                int slot = (n == d_lo) ? 0 : 1;
                f32x2 w; w[0] = s0; w[1] = s1;
                __builtin_nontemporal_store(
                    w, (f32x2*)(spill + ((size_t)(t * 2 + slot)) * D_MSG + lane * 2));
            }
        }
    }
}

// ---------------------------------------------------------------------------
// cleanup: finish boundary nodes (sum their per-tile spill rows) and write
// zero rows for degree-0 nodes. Grid-stride (1600 blocks).
// ---------------------------------------------------------------------------
__global__ __launch_bounds__(256) void cleanup_kernel(
    const i32x4* __restrict__ meta, const int* __restrict__ base,
    const int* __restrict__ cnt, const float* __restrict__ spill,
    unsigned int* __restrict__ meanB32)
{
    const int wav = threadIdx.x >> 6;
    const int lane = threadIdx.x & 63;
    const int nstride = gridDim.x * 4;
    for (int n = blockIdx.x * 4 + wav; n < N_NODES; n += nstride) {
        const int c = cnt[n];
        float s0 = 0.f, s1 = 0.f;
        if (c > 0) {
            const int b = base[n];
            const int t0 = b >> 6, t1 = (b + c - 1) >> 6;
            if (t0 == t1) continue;   // interior: already written by msg_fused
            for (int t = t0; t <= t1; ++t) {
                const int slot = (((const int*)&meta[t * TILE])[2] == n) ? 0 : 1;
                const float* sp = spill + ((size_t)(t * 2 + slot)) * D_MSG + lane * 2;
                s0 += sp[0]; s1 += sp[1];
            }
        }
        meanB32[(size_t)n * 64 + lane] = (unsigned)f2bf(s0) | ((unsigned)f2bf(s1) << 16);
    }
}

// ---------------------------------------------------------------------------
// Phase C: node GEMM, all-bf16 fragment loads. 782 blocks x 128 nodes
// (2 blocks/CU with 64KB LDS -> better latency overlap than 391x256).
// ---------------------------------------------------------------------------
__global__ __launch_bounds__(256) void node_gemm_kernel(
    const unsigned short* __restrict__ nodeB, const unsigned short* __restrict__ meanB,
    const unsigned short* __restrict__ WtU, const float* __restrict__ b_upd,
    float* __restrict__ out)
{
    __shared__ unsigned short sW[128 * K2];   // 65536 B

    for (int idx = threadIdx.x; idx < 128 * 32; idx += 256) {
        int o = idx >> 5, ch = idx & 31;
        *(uint4*)&sW[o * K2 + (ch ^ (o & 7)) * 8] = *(const uint4*)&WtU[o * K2 + ch * 8];
    }

    const int lane = threadIdx.x & 63;
    const int wav  = threadIdx.x >> 6;
    const int j = lane & 15;
    const int q = lane >> 4;
    const int rs = j & 7;

    float bias[32];
#pragma unroll
    for (int mt = 0; mt < 8; ++mt)
#pragma unroll
        for (int r = 0; r < 4; ++r) bias[mt * 4 + r] = b_upd[mt * 16 + q * 4 + r];
    __syncthreads();

    const int n0w = blockIdx.x * 128 + wav * 32;

#pragma unroll 1
    for (int g = 0; g < 2; ++g) {
        const int n = n0w + g * 16 + j;
        const bool valid = (n < N_NODES);
        const size_t nn = valid ? (size_t)n : 0;

        frag8 bfr[8];
        const unsigned short* nrow = nodeB + nn * D_NODE;
#pragma unroll
        for (int kc = 0; kc < 4; ++kc)
            bfr[kc] = *(const frag8*)&nrow[kc * 32 + q * 8];
        const unsigned short* mrow = meanB + nn * D_MSG;
#pragma unroll
        for (int kc = 0; kc < 4; ++kc)
            bfr[4 + kc] = *(const frag8*)&mrow[kc * 32 + q * 8];

        facc acc[8];
#pragma unroll
        for (int mt = 0; mt < 8; ++mt) { facc z = {0.f, 0.f, 0.f, 0.f}; acc[mt] = z; }

#pragma unroll
        for (int mt = 0; mt < 8; ++mt) {
            const unsigned short* wrow = &sW[(mt * 16 + j) * K2];
#pragma unroll
            for (int kc = 0; kc < 8; ++kc) {
                frag8 a = *(const frag8*)&wrow[((kc * 4 + q) ^ rs) * 8];
                acc[mt] = __builtin_amdgcn_mfma_f32_16x16x32_bf16(a, bfr[kc], acc[mt], 0, 0, 0);
            }
        }

        if (valid) {
            float* orow = out + (size_t)n * D_OUT;
#pragma unroll
            for (int mt = 0; mt < 8; ++mt)
#pragma unroll
                for (int r = 0; r < 4; ++r)
                    orow[mt * 16 + q * 4 + r] = fmaxf(acc[mt][r] + bias[mt * 4 + r], 0.f);
        }
    }
}

// ===========================================================================
// FALLBACK PATH (round-3 style, meta-packed): fused msg+aggregate if ws small.
// ===========================================================================
__global__ void prep_w_kernel(const float* __restrict__ Wm, const float* __restrict__ Wu,
                              unsigned short* __restrict__ WtM, unsigned short* __restrict__ WtU) {
    int idx0 = blockIdx.x * blockDim.x + threadIdx.x;
    int stride = gridDim.x * blockDim.x;
    for (int idx = idx0; idx < 128 * K1; idx += stride) {
        int o = idx / K1, k = idx - o * K1;
        WtM[idx] = f2bf(Wm[k * D_MSG + o]);
    }
    for (int idx = idx0; idx < 128 * K2; idx += stride) {
        int o = idx >> 8, k = idx & 255;
        WtU[idx] = f2bf(Wu[k * D_OUT + o]);
    }
}

__global__ void hist_kernel(const int* __restrict__ dst, int* __restrict__ cnt) {
    int idx0 = blockIdx.x * blockDim.x + threadIdx.x;
    int stride = gridDim.x * blockDim.x;
    for (int e = idx0; e < N_EDGES; e += stride) {
        int d = min(max(dst[e], 0), N_NODES - 1);
        atomicAdd(&cnt[d], 1);
    }
}

__global__ __launch_bounds__(256) void msg_agg_kernel_fb(
    const float* __restrict__ node_emb, const i32x4* __restrict__ meta,
    const float* __restrict__ edge_emb, const unsigned short* __restrict__ WtM,
    const float* __restrict__ b_msg, const int* __restrict__ cnt,
    float* __restrict__ mean)
{
    __shared__ unsigned short sW[128 * K1];

    for (int idx = threadIdx.x; idx < 128 * 24; idx += 256) {
        int o = idx / 24, ch = idx % 24;
        *(uint4*)&sW[o * K1 + (ch ^ (o & 7)) * 8] = *(const uint4*)&WtM[o * K1 + ch * 8];
    }

    const int lane = threadIdx.x & 63;
    const int wav  = threadIdx.x >> 6;
    const int j = lane & 15;
    const int q = lane >> 4;

    float bias[32];
#pragma unroll
    for (int mt = 0; mt < 8; ++mt)
#pragma unroll
        for (int r = 0; r < 4; ++r) bias[mt * 4 + r] = b_msg[mt * 16 + q * 4 + r];
    __syncthreads();

    const int e0w = blockIdx.x * 256 + wav * 64;
    float carry[32];
    int carry_d = -1;

#pragma unroll 1
    for (int g = 0; g < 4; ++g) {
        const int e = e0w + g * 16 + j;
        const i32x4 m = meta[e];
        const int p = m[0];
        const int d = m[2];
        const int sp = min(max(m[1], 0), N_NODES - 1);
        const float invc = 1.0f / (float)cnt[d];

        frag8 bfr[6];
        const float* nrow = node_emb + (size_t)sp * D_NODE;
#pragma unroll
        for (int kc = 0; kc < 4; ++kc) {
            float4 a = *(const float4*)&nrow[kc * 32 + q * 8];
            float4 c = *(const float4*)&nrow[kc * 32 + q * 8 + 4];
            bfr[kc] = pack8(a, c);
        }
        const float* erow = edge_emb + (size_t)p * D_EDGE;
#pragma unroll
        for (int kc = 0; kc < 2; ++kc) {
            float4 a = *(const float4*)&erow[kc * 32 + q * 8];
            float4 c = *(const float4*)&erow[kc * 32 + q * 8 + 4];
            bfr[4 + kc] = pack8(a, c);
        }

        facc acc[8];
#pragma unroll
        for (int mt = 0; mt < 8; ++mt) { facc z = {0.f, 0.f, 0.f, 0.f}; acc[mt] = z; }

#pragma unroll
        for (int mt = 0; mt < 8; ++mt) {
            const unsigned short* wrow = &sW[(mt * 16 + j) * K1];
            const int rs = j & 7;
#pragma unroll
            for (int kc = 0; kc < 6; ++kc) {
                frag8 a = *(const frag8*)&wrow[((kc * 4 + q) ^ rs) * 8];
                acc[mt] = __builtin_amdgcn_mfma_f32_16x16x32_bf16(a, bfr[kc], acc[mt], 0, 0, 0);
            }
        }

        float v[32];
#pragma unroll
        for (int mt = 0; mt < 8; ++mt)
#pragma unroll
            for (int r = 0; r < 4; ++r) {
                float t = acc[mt][r] + bias[mt * 4 + r];
                v[mt * 4 + r] = fmaxf(t, 0.f) * invc;
            }

        int dprev = __shfl_up(d, 1, 16);
        int head = (j == 0 || d != dprev) ? 1 : 0;
        int seg = head;
#pragma unroll
        for (int s = 1; s < 16; s <<= 1) { int t = __shfl_up(seg, s, 16); if (j >= s) seg += t; }
        int sg1 = __shfl_up(seg, 1, 16);
        int sg2 = __shfl_up(seg, 2, 16);
        int sg4 = __shfl_up(seg, 4, 16);
        int sg8 = __shfl_up(seg, 8, 16);
        bool ok1 = (j >= 1) && (sg1 == seg);
        bool ok2 = (j >= 2) && (sg2 == seg);
        bool ok4 = (j >= 4) && (sg4 == seg);
        bool ok8 = (j >= 8) && (sg8 == seg);

#pragma unroll
        for (int i = 0; i < 32; ++i) { float t = __shfl_up(v[i], 1, 16); if (ok1) v[i] += t; }
#pragma unroll
        for (int i = 0; i < 32; ++i) { float t = __shfl_up(v[i], 2, 16); if (ok2) v[i] += t; }
#pragma unroll
        for (int i = 0; i < 32; ++i) { float t = __shfl_up(v[i], 4, 16); if (ok4) v[i] += t; }
#pragma unroll
        for (int i = 0; i < 32; ++i) { float t = __shfl_up(v[i], 8, 16); if (ok8) v[i] += t; }

        int d0 = __shfl(d, 0, 16);
        if (g > 0) {
            if (d0 != carry_d) {
                if (j == 0) {
                    float* mrow = mean + (size_t)carry_d * D_MSG;
#pragma unroll
                    for (int mt = 0; mt < 8; ++mt)
#pragma unroll
                        for (int r = 0; r < 4; ++r)
                            atomicAdd(&mrow[mt * 16 + q * 4 + r], carry[mt * 4 + r]);
                }
            } else if (seg == 1) {
#pragma unroll
                for (int i = 0; i < 32; ++i) v[i] += carry[i];
            }
        }

#pragma unroll
        for (int i = 0; i < 32; ++i) carry[i] = __shfl(v[i], 15, 16);
        carry_d = __shfl(d, 15, 16);

        int dnext = __shfl_down(d, 1, 16);
        bool tail = (j < 15) ? (dnext != d) : (g == 3);
        if (tail) {
            float* mrow = mean + (size_t)d * D_MSG;
#pragma unroll
            for (int mt = 0; mt < 8; ++mt)
#pragma unroll
                for (int r = 0; r < 4; ++r)
                    atomicAdd(&mrow[mt * 16 + q * 4 + r], v[mt * 4 + r]);
        }
    }
}

__global__ __launch_bounds__(256) void node_kernel_fb(
    const float* __restrict__ node_emb, const float* __restrict__ mean,
    const unsigned short* __restrict__ WtU, const float* __restrict__ b_upd,
    float* __restrict__ out)
{
    __shared__ unsigned short sW[128 * K2];

    for (int idx = threadIdx.x; idx < 128 * 32; idx += 256) {
        int o = idx >> 5, ch = idx & 31;
        *(uint4*)&sW[o * K2 + (ch ^ (o & 7)) * 8] = *(const uint4*)&WtU[o * K2 + ch * 8];
    }

    const int lane = threadIdx.x & 63;
    const int wav  = threadIdx.x >> 6;
    const int j = lane & 15;
    const int q = lane >> 4;

    float bias[32];
#pragma unroll
    for (int mt = 0; mt < 8; ++mt)
#pragma unroll
        for (int r = 0; r < 4; ++r) bias[mt * 4 + r] = b_upd[mt * 16 + q * 4 + r];
    __syncthreads();

    const int n0w = blockIdx.x * 256 + wav * 64;

#pragma unroll 1
    for (int g = 0; g < 4; ++g) {
        const int n = n0w + g * 16 + j;
        const bool valid = (n < N_NODES);
        const size_t nn = valid ? (size_t)n : 0;

        frag8 bfr[8];
        const float* nrow = node_emb + nn * D_NODE;
#pragma unroll
        for (int kc = 0; kc < 4; ++kc) {
            float4 a = *(const float4*)&nrow[kc * 32 + q * 8];
            float4 c = *(const float4*)&nrow[kc * 32 + q * 8 + 4];
            bfr[kc] = pack8(a, c);
        }
        const float* mrow = mean + nn * D_MSG;
#pragma unroll
        for (int kc = 0; kc < 4; ++kc) {
            float4 a = *(const float4*)&mrow[kc * 32 + q * 8];
            float4 c = *(const float4*)&mrow[kc * 32 + q * 8 + 4];
            bfr[4 + kc] = pack8(a, c);
        }

        facc acc[8];
#pragma unroll
        for (int mt = 0; mt < 8; ++mt) { facc z = {0.f, 0.f, 0.f, 0.f}; acc[mt] = z; }

#pragma unroll
        for (int mt = 0; mt < 8; ++mt) {
            const unsigned short* wrow = &sW[(mt * 16 + j) * K2];
            const int rs = j & 7;
#pragma unroll
            for (int kc = 0; kc < 8; ++kc) {
                frag8 a = *(const frag8*)&wrow[((kc * 4 + q) ^ rs) * 8];
                acc[mt] = __builtin_amdgcn_mfma_f32_16x16x32_bf16(a, bfr[kc], acc[mt], 0, 0, 0);
            }
        }

        if (valid) {
            float* orow = out + (size_t)n * D_OUT;
#pragma unroll
            for (int mt = 0; mt < 8; ++mt)
#pragma unroll
                for (int r = 0; r < 4; ++r)
                    orow[mt * 16 + q * 4 + r] = fmaxf(acc[mt][r] + bias[mt * 4 + r], 0.f);
        }
    }
}

extern "C" void kernel_launch(void* const* d_in, const int* in_sizes, int n_in,
                              void* d_out, int out_size, void* d_ws, size_t ws_size,
                              hipStream_t stream) {
    const float* node_emb = (const float*)d_in[0];
    const int*   edge_idx = (const int*)d_in[1];
    const float* edge_emb = (const float*)d_in[2];
    const float* W_msg    = (const float*)d_in[3];
    const float* b_msg    = (const float*)d_in[4];
    const float* W_upd    = (const float*)d_in[5];
    const float* b_upd    = (const float*)d_in[6];
    float* out = (float*)d_out;

    const int* src = edge_idx;
    const int* dst = edge_idx + N_EDGES;

    char* W = (char*)d_ws;

    if (ws_size >= 104000000ULL) {
        // ---- FAST PATH ----
        unsigned short* meanB = (unsigned short*)(W + 0);         // 25,600,000
        int* cnt     = (int*)(W + 25600000);                      //    400,000
        int* cursor  = (int*)(W + 26000000);                      //    400,000
        int* base    = (int*)(W + 26400000);                      //    400,000
        int* part    = (int*)(W + 26800000);                      //        512
        i32x4* meta  = (i32x4*)(W + 26800512);                    // 25,600,000
        unsigned short* WtM   = (unsigned short*)(W + 52400512);  //     49,152
        unsigned short* WtU   = (unsigned short*)(W + 52449664);  //     65,536
        unsigned short* nodeB = (unsigned short*)(W + 52515200);  // 25,600,000
        float* spill = (float*)(W + 78115200);                    //  25,600,000

        // zero only cnt + cursor
        hipMemsetAsync(W + 25600000, 0, 800000, stream);

        prep_all_kernel<<<2048, 256, 0, stream>>>(W_msg, W_upd, node_emb, dst,
                                                  WtM, WtU, (unsigned int*)nodeB, cnt);
        scan_blocks<<<NSB, 1024, 0, stream>>>(cnt, base, part);
        scan_add<<<NSB, 1024, 0, stream>>>(base, part);
        scatter_kernel<<<1024, 256, 0, stream>>>(dst, src, base, cursor, meta);
        msg_fused_kernel<<<2048, 256, 0, stream>>>(nodeB, meta, edge_emb,
                                                   WtM, b_msg, base, cnt,
                                                   (unsigned int*)meanB, spill);
        cleanup_kernel<<<1600, 256, 0, stream>>>(meta, base, cnt, spill,
                                                 (unsigned int*)meanB);
        node_gemm_kernel<<<782, 256, 0, stream>>>(nodeB, meanB, WtU, b_upd, out);
    } else {
        // ---- FALLBACK ----
        float* mean  = (float*)W;                               // 51,200,000
        int* cnt     = (int*)(W + 51200000);
        int* cursor  = (int*)(W + 51600000);
        int* base    = (int*)(W + 52000000);
        int* part    = (int*)(W + 52400000);
        i32x4* meta  = (i32x4*)(W + 52400512);                  // 25,600,000
        unsigned short* WtM = (unsigned short*)(W + 78000512);
        unsigned short* WtU = (unsigned short*)(W + 78049664);

        hipMemsetAsync(d_ws, 0, 52000000, stream);

        prep_w_kernel<<<224, 256, 0, stream>>>(W_msg, W_upd, WtM, WtU);
        hist_kernel<<<1024, 256, 0, stream>>>(dst, cnt);
        scan_blocks<<<NSB, 1024, 0, stream>>>(cnt, base, part);
        scan_add<<<NSB, 1024, 0, stream>>>(base, part);
        scatter_kernel<<<1024, 256, 0, stream>>>(dst, src, base, cursor, meta);
        msg_agg_kernel_fb<<<6250, 256, 0, stream>>>(node_emb, meta, edge_emb, WtM,
                                                    b_msg, cnt, mean);
        node_kernel_fb<<<391, 256, 0, stream>>>(node_emb, mean, WtU, b_upd, out);
    }
}

// Round 12
// 570.920 us; speedup vs baseline: 1.0863x; 1.0313x over previous
//
#include <hip/hip_runtime.h>
#include <hip/hip_bf16.h>

#define N_NODES 100000
#define N_EDGES 1600000
#define D_NODE 128
#define D_EDGE 64
#define D_MSG 128
#define K1 192   // NODE_DIM + EDGE_DIM
#define K2 256   // NODE_DIM + MSG_DIM
#define D_OUT 128
#define NSB 98   // scan blocks: ceil(100000/1024)
#define TILE 64
#define NT (N_EDGES / TILE)   // 25000 exact

using frag8 = __attribute__((ext_vector_type(8))) short;   // 8 bf16 (4 VGPRs)
using facc  = __attribute__((ext_vector_type(4))) float;   // 4 f32 acc
typedef int   i32x4 __attribute__((ext_vector_type(4)));
typedef float f32x2 __attribute__((ext_vector_type(2)));
typedef float f32x4v __attribute__((ext_vector_type(4)));

static __device__ __forceinline__ unsigned short f2bf(float f) {
    unsigned int u = __float_as_uint(f);
    u = u + 0x7fffu + ((u >> 16) & 1u);   // RNE
    return (unsigned short)(u >> 16);
}
static __device__ __forceinline__ float bflo(unsigned int u) { return __uint_as_float(u << 16); }
static __device__ __forceinline__ float bfhi(unsigned int u) { return __uint_as_float(u & 0xffff0000u); }

union F8 { unsigned short s[8]; frag8 f; uint4 u4; };

static __device__ __forceinline__ frag8 pack8(float4 a, float4 b) {
    F8 u;
    u.s[0] = f2bf(a.x); u.s[1] = f2bf(a.y); u.s[2] = f2bf(a.z); u.s[3] = f2bf(a.w);
    u.s[4] = f2bf(b.x); u.s[5] = f2bf(b.y); u.s[6] = f2bf(b.z); u.s[7] = f2bf(b.w);
    return u.f;
}

// ---------------------------------------------------------------------------
// prep_all: W transpose->bf16, node_emb->bf16 (float4 vectorized), dst hist.
// ---------------------------------------------------------------------------
__global__ void prep_all_kernel(const float* __restrict__ Wm, const float* __restrict__ Wu,
                                const float* __restrict__ node_emb, const int* __restrict__ dst,
                                unsigned int* __restrict__ nodeB32, int* __restrict__ cnt,
                                unsigned short* __restrict__ WtM, unsigned short* __restrict__ WtU) {
    int idx0 = blockIdx.x * blockDim.x + threadIdx.x;
    int stride = gridDim.x * blockDim.x;
    for (int idx = idx0; idx < 128 * K1; idx += stride) {
        int o = idx / K1, k = idx - o * K1;
        WtM[idx] = f2bf(Wm[k * D_MSG + o]);
    }
    for (int idx = idx0; idx < 128 * K2; idx += stride) {
        int o = idx >> 8, k = idx & 255;
        WtU[idx] = f2bf(Wu[k * D_OUT + o]);
    }
    const int total = N_NODES * 32;   // float4 quads
    for (int i = idx0; i < total; i += stride) {
        float4 v = *(const float4*)&node_emb[(size_t)i * 4];
        uint2 w;
        w.x = (unsigned)f2bf(v.x) | ((unsigned)f2bf(v.y) << 16);
        w.y = (unsigned)f2bf(v.z) | ((unsigned)f2bf(v.w) << 16);
        *(uint2*)&nodeB32[(size_t)i * 2] = w;
    }
    for (int e = idx0; e < N_EDGES; e += stride) {
        int d = min(max(dst[e], 0), N_NODES - 1);
        atomicAdd(&cnt[d], 1);
    }
}

__global__ __launch_bounds__(1024) void scan_blocks(const int* __restrict__ cnt,
                                                    int* __restrict__ base,
                                                    int* __restrict__ part) {
    __shared__ int sh[1024];
    int i = blockIdx.x * 1024 + threadIdx.x;
    int c = (i < N_NODES) ? cnt[i] : 0;
    sh[threadIdx.x] = c;
    __syncthreads();
    for (int s = 1; s < 1024; s <<= 1) {
        int t = (threadIdx.x >= s) ? sh[threadIdx.x - s] : 0;
        __syncthreads();
        sh[threadIdx.x] += t;
        __syncthreads();
    }
    if (i < N_NODES) base[i] = sh[threadIdx.x] - c;   // exclusive within block
    if (threadIdx.x == 1023) part[blockIdx.x] = sh[1023];   // raw block sum
}

// scan_add: computes this block's partial-prefix in-wave
__global__ __launch_bounds__(1024) void scan_add(int* __restrict__ base, const int* __restrict__ part) {
    __shared__ int soff;
    if (threadIdx.x < 64) {
        int l = threadIdx.x;
        int v = 0;
        if (l < blockIdx.x) v += part[l];
        if (l + 64 < blockIdx.x) v += part[l + 64];
#pragma unroll
        for (int s = 32; s; s >>= 1) v += __shfl_down(v, s, 64);
        if (l == 0) soff = v;
    }
    __syncthreads();
    int i = blockIdx.x * 1024 + threadIdx.x;
    if (i < N_NODES) base[i] += soff;
}

// ---------------------------------------------------------------------------
// scatter: bins edges by dst; ONE packed int4 nt-store per edge
// meta[pos] = {orig_e, src[e], d, 0}
// ---------------------------------------------------------------------------
__global__ void scatter_kernel(const int* __restrict__ dst, const int* __restrict__ src,
                               const int* __restrict__ base, int* __restrict__ cursor,
                               i32x4* __restrict__ meta) {
    int idx0 = blockIdx.x * blockDim.x + threadIdx.x;
    int stride = gridDim.x * blockDim.x;
    for (int e = idx0; e < N_EDGES; e += stride) {
        int d = min(max(dst[e], 0), N_NODES - 1);
        int pos = base[d] + atomicAdd(&cursor[d], 1);
        i32x4 m; m[0] = e; m[1] = src[e]; m[2] = d; m[3] = 0;
        __builtin_nontemporal_store(m, &meta[pos]);
    }
}

// ---------------------------------------------------------------------------
// FUSED Phase A: per 64-edge tile: msg GEMM (W in regs, inputs staged in
// XOR-swizzled LDS) -> msg tile in LDS -> in-block per-node mean.
// launch_bounds (256,3): r6-vs-r11 A/B showed 4 blocks/CU thrashes L2
// (FETCH 445->707 MB) — the random-gather working set needs the cache.
// ---------------------------------------------------------------------------
__global__ __launch_bounds__(256, 3) void msg_fused_kernel(
    const unsigned short* __restrict__ nodeB, const i32x4* __restrict__ meta,
    const float* __restrict__ edge_emb, const unsigned short* __restrict__ WtM,
    const float* __restrict__ b_msg, const int* __restrict__ base,
    const int* __restrict__ cnt, unsigned int* __restrict__ meanB32,
    float* __restrict__ spill)
{
    __shared__ unsigned short sIn[TILE][192];    // 24576 B; 16B chunks XOR row&7
    __shared__ unsigned short sMsg[TILE][128];   // 16384 B; 8B chunks XOR row&7

    const int lane = threadIdx.x & 63;
    const int wav  = threadIdx.x >> 6;
    const int j = lane & 15;
    const int q = lane >> 4;

    // W slice (out rows 32*wav .. 32*wav+31) in registers
    frag8 wfr[2][6];
#pragma unroll
    for (int m2 = 0; m2 < 2; ++m2) {
        const unsigned short* wrow = WtM + ((wav * 2 + m2) * 16 + j) * K1;
#pragma unroll
        for (int kc = 0; kc < 6; ++kc)
            wfr[m2][kc] = *(const frag8*)&wrow[(kc * 4 + q) * 8];
    }
    float bias[2][4];
#pragma unroll
    for (int m2 = 0; m2 < 2; ++m2)
#pragma unroll
        for (int r = 0; r < 4; ++r) bias[m2][r] = b_msg[(wav * 2 + m2) * 16 + q * 4 + r];

    // staging role: thread t covers edge row eL = t>>2, quarter qt = t&3
    const int eL = threadIdx.x >> 2;
    const int qt = threadIdx.x & 3;
    const int swz = eL & 7;

    uint4  nst[4];    // node part: 64B bf16 (cached gather)
    float4 est[4];    // edge part: 64B f32 (cached)

    const int t0 = blockIdx.x;

    // prologue: issue loads for tile t0
    {
        const int e = t0 * TILE + eL;
        const i32x4 m = meta[e];
        const int sp = min(max(m[1], 0), N_NODES - 1);
        const unsigned short* nrow = nodeB + (size_t)sp * D_NODE + qt * 32;
#pragma unroll
        for (int i = 0; i < 4; ++i) nst[i] = *(const uint4*)&nrow[i * 8];
        const float* erow = edge_emb + (size_t)m[0] * D_EDGE + qt * 16;
#pragma unroll
        for (int i = 0; i < 4; ++i) est[i] = *(const float4*)&erow[i * 4];
    }

#pragma unroll 1
    for (int t = t0; t < NT; t += gridDim.x) {
        const int e0 = t * TILE;

        __syncthreads();   // (a) prior GEMM + reduction done; sIn free

        // write staged tile into sIn (XOR-swizzled 16B chunks)
        {
            unsigned short* drow = &sIn[eL][0];
#pragma unroll
            for (int i = 0; i < 4; ++i)
                *(uint4*)&drow[((4 * qt + i) ^ swz) * 8] = nst[i];
#pragma unroll
            for (int h = 0; h < 2; ++h) {
                F8 u;
                u.f = pack8(est[h * 2], est[h * 2 + 1]);
                *(uint4*)&drow[((16 + 2 * qt + h) ^ swz) * 8] = u.u4;
            }
        }
        __syncthreads();   // (b) sIn ready

        // issue next tile's loads early (latency hides under compute)
        const int tn = t + gridDim.x;
        if (tn < NT) {
            const int e = tn * TILE + eL;
            const i32x4 m = meta[e];
            const int sp = min(max(m[1], 0), N_NODES - 1);
            const unsigned short* nrow = nodeB + (size_t)sp * D_NODE + qt * 32;
#pragma unroll
            for (int i = 0; i < 4; ++i) nst[i] = *(const uint4*)&nrow[i * 8];
            const float* erow = edge_emb + (size_t)m[0] * D_EDGE + qt * 16;
#pragma unroll
            for (int i = 0; i < 4; ++i) est[i] = *(const float4*)&erow[i * 4];
        }

        // GEMM: wave computes outs 32*wav..+31 for all 64 edges
        facc acc[2][4];
#pragma unroll
        for (int m2 = 0; m2 < 2; ++m2)
#pragma unroll
            for (int eg = 0; eg < 4; ++eg) { facc z = {0.f,0.f,0.f,0.f}; acc[m2][eg] = z; }

        const int rsw = j & 7;
#pragma unroll
        for (int eg = 0; eg < 4; ++eg) {
            const unsigned short* irow = &sIn[eg * 16 + j][0];
#pragma unroll
            for (int kc = 0; kc < 6; ++kc) {
                frag8 b = *(const frag8*)&irow[((4 * kc + q) ^ rsw) * 8];
                acc[0][eg] = __builtin_amdgcn_mfma_f32_16x16x32_bf16(wfr[0][kc], b, acc[0][eg], 0, 0, 0);
                acc[1][eg] = __builtin_amdgcn_mfma_f32_16x16x32_bf16(wfr[1][kc], b, acc[1][eg], 0, 0, 0);
            }
        }

        // epilogue: bias+relu+cvt bf16 -> sMsg (8B chunks XOR row&7)
#pragma unroll
        for (int eg = 0; eg < 4; ++eg) {
            unsigned short* mrow = &sMsg[eg * 16 + j][0];
#pragma unroll
            for (int m2 = 0; m2 < 2; ++m2) {
                float v0 = fmaxf(acc[m2][eg][0] + bias[m2][0], 0.f);
                float v1 = fmaxf(acc[m2][eg][1] + bias[m2][1], 0.f);
                float v2 = fmaxf(acc[m2][eg][2] + bias[m2][2], 0.f);
                float v3 = fmaxf(acc[m2][eg][3] + bias[m2][3], 0.f);
                uint2 w;
                w.x = (unsigned)f2bf(v0) | ((unsigned)f2bf(v1) << 16);
                w.y = (unsigned)f2bf(v2) | ((unsigned)f2bf(v3) << 16);
                int c64 = wav * 8 + m2 * 4 + q;        // u64 index 0..31
                *(uint2*)&mrow[(c64 ^ rsw) * 4] = w;
            }
        }
        __syncthreads();   // (c) sMsg ready

        // in-block mean finish: wave handles nodes d_lo+wav, +4, ...
        const int d_lo = ((const int*)&meta[e0])[2];
        const int d_hi = ((const int*)&meta[e0 + TILE - 1])[2];
        for (int n = d_lo + wav; n <= d_hi; n += 4) {
            const int b = base[n];
            const int c = cnt[n];
            const int lo = max(b - e0, 0);
            const int hi = min(b + c - e0, TILE);
            float s0 = 0.f, s1 = 0.f;
            for (int r = lo; r < hi; ++r) {
                const unsigned* mr = (const unsigned*)&sMsg[r][0];
                unsigned u = mr[(((lane >> 1) ^ (r & 7)) << 1) | (lane & 1)];
                s0 += bflo(u); s1 += bfhi(u);
            }
            const float inv = 1.0f / fmaxf((float)c, 1.0f);
            s0 *= inv; s1 *= inv;
            if (b >= e0 && b + c <= e0 + TILE) {
                // interior: exclusive owner, direct bf16 mean row write (nt)
                unsigned int w = (unsigned)f2bf(s0) | ((unsigned)f2bf(s1) << 16);
                __builtin_nontemporal_store(w, &meanB32[(size_t)n * 64 + lane]);
            } else {
                // non-interior: deterministic f32 spill slot (NO atomics, nt)
                int slot = (n == d_lo) ? 0 : 1;
                f32x2 w; w[0] = s0; w[1] = s1;
                __builtin_nontemporal_store(
                    w, (f32x2*)(spill + ((size_t)(t * 2 + slot)) * D_MSG + lane * 2));
            }
        }
    }
}

// ---------------------------------------------------------------------------
// cleanup: finish boundary nodes (sum their per-tile spill rows) and write
// zero rows for degree-0 nodes. Grid-stride; nt loads on spill stream.
// ---------------------------------------------------------------------------
__global__ __launch_bounds__(256) void cleanup_kernel(
    const i32x4* __restrict__ meta, const int* __restrict__ base,
    const int* __restrict__ cnt, const float* __restrict__ spill,
    unsigned int* __restrict__ meanB32)
{
    const int wav = threadIdx.x >> 6;
    const int lane = threadIdx.x & 63;
    const int nstride = gridDim.x * 4;
    for (int n = blockIdx.x * 4 + wav; n < N_NODES; n += nstride) {
        const int c = cnt[n];
        float s0 = 0.f, s1 = 0.f;
        if (c > 0) {
            const int b = base[n];
            const int t0 = b >> 6, t1 = (b + c - 1) >> 6;
            if (t0 == t1) continue;   // interior: already written by msg_fused
            for (int t = t0; t <= t1; ++t) {
                const int slot = (((const int*)&meta[t * TILE])[2] == n) ? 0 : 1;
                f32x2 v = __builtin_nontemporal_load(
                    (const f32x2*)(spill + ((size_t)(t * 2 + slot)) * D_MSG + lane * 2));
                s0 += v[0]; s1 += v[1];
            }
        }
        meanB32[(size_t)n * 64 + lane] = (unsigned)f2bf(s0) | ((unsigned)f2bf(s1) << 16);
    }
}

// ---------------------------------------------------------------------------
// Phase C: node GEMM, all-bf16 fragment loads; nt-stores for write-once out.
// ---------------------------------------------------------------------------
__global__ __launch_bounds__(256) void node_gemm_kernel(
    const unsigned short* __restrict__ nodeB, const unsigned short* __restrict__ meanB,
    const unsigned short* __restrict__ WtU, const float* __restrict__ b_upd,
    float* __restrict__ out)
{
    __shared__ unsigned short sW[128 * K2];   // 65536 B

    for (int idx = threadIdx.x; idx < 128 * 32; idx += 256) {
        int o = idx >> 5, ch = idx & 31;
        *(uint4*)&sW[o * K2 + (ch ^ (o & 7)) * 8] = *(const uint4*)&WtU[o * K2 + ch * 8];
    }

    const int lane = threadIdx.x & 63;
    const int wav  = threadIdx.x >> 6;
    const int j = lane & 15;
    const int q = lane >> 4;
    const int rs = j & 7;

    float bias[32];
#pragma unroll
    for (int mt = 0; mt < 8; ++mt)
#pragma unroll
        for (int r = 0; r < 4; ++r) bias[mt * 4 + r] = b_upd[mt * 16 + q * 4 + r];
    __syncthreads();

    const int n0w = blockIdx.x * 128 + wav * 32;

#pragma unroll 1
    for (int g = 0; g < 2; ++g) {
        const int n = n0w + g * 16 + j;
        const bool valid = (n < N_NODES);
        const size_t nn = valid ? (size_t)n : 0;

        frag8 bfr[8];
        const unsigned short* nrow = nodeB + nn * D_NODE;
#pragma unroll
        for (int kc = 0; kc < 4; ++kc)
            bfr[kc] = *(const frag8*)&nrow[kc * 32 + q * 8];
        const unsigned short* mrow = meanB + nn * D_MSG;
#pragma unroll
        for (int kc = 0; kc < 4; ++kc)
            bfr[4 + kc] = *(const frag8*)&mrow[kc * 32 + q * 8];

        facc acc[8];
#pragma unroll
        for (int mt = 0; mt < 8; ++mt) { facc z = {0.f, 0.f, 0.f, 0.f}; acc[mt] = z; }

#pragma unroll
        for (int mt = 0; mt < 8; ++mt) {
            const unsigned short* wrow = &sW[(mt * 16 + j) * K2];
#pragma unroll
            for (int kc = 0; kc < 8; ++kc) {
                frag8 a = *(const frag8*)&wrow[((kc * 4 + q) ^ rs) * 8];
                acc[mt] = __builtin_amdgcn_mfma_f32_16x16x32_bf16(a, bfr[kc], acc[mt], 0, 0, 0);
            }
        }

        if (valid) {
            float* orow = out + (size_t)n * D_OUT;
#pragma unroll
            for (int mt = 0; mt < 8; ++mt) {
                f32x4v w;
                w[0] = fmaxf(acc[mt][0] + bias[mt * 4 + 0], 0.f);
                w[1] = fmaxf(acc[mt][1] + bias[mt * 4 + 1], 0.f);
                w[2] = fmaxf(acc[mt][2] + bias[mt * 4 + 2], 0.f);
                w[3] = fmaxf(acc[mt][3] + bias[mt * 4 + 3], 0.f);
                __builtin_nontemporal_store(w, (f32x4v*)&orow[mt * 16 + q * 4]);
            }
        }
    }
}

// ===========================================================================
// FALLBACK PATH (round-3 style, meta-packed): fused msg+aggregate if ws small.
// ===========================================================================
__global__ void prep_w_kernel(const float* __restrict__ Wm, const float* __restrict__ Wu,
                              unsigned short* __restrict__ WtM, unsigned short* __restrict__ WtU) {
    int idx0 = blockIdx.x * blockDim.x + threadIdx.x;
    int stride = gridDim.x * blockDim.x;
    for (int idx = idx0; idx < 128 * K1; idx += stride) {
        int o = idx / K1, k = idx - o * K1;
        WtM[idx] = f2bf(Wm[k * D_MSG + o]);
    }
    for (int idx = idx0; idx < 128 * K2; idx += stride) {
        int o = idx >> 8, k = idx & 255;
        WtU[idx] = f2bf(Wu[k * D_OUT + o]);
    }
}

__global__ void hist_kernel(const int* __restrict__ dst, int* __restrict__ cnt) {
    int idx0 = blockIdx.x * blockDim.x + threadIdx.x;
    int stride = gridDim.x * blockDim.x;
    for (int e = idx0; e < N_EDGES; e += stride) {
        int d = min(max(dst[e], 0), N_NODES - 1);
        atomicAdd(&cnt[d], 1);
    }
}

__global__ __launch_bounds__(256) void msg_agg_kernel_fb(
    const float* __restrict__ node_emb, const i32x4* __restrict__ meta,
    const float* __restrict__ edge_emb, const unsigned short* __restrict__ WtM,
    const float* __restrict__ b_msg, const int* __restrict__ cnt,
    float* __restrict__ mean)
{
    __shared__ unsigned short sW[128 * K1];

    for (int idx = threadIdx.x; idx < 128 * 24; idx += 256) {
        int o = idx / 24, ch = idx % 24;
        *(uint4*)&sW[o * K1 + (ch ^ (o & 7)) * 8] = *(const uint4*)&WtM[o * K1 + ch * 8];
    }

    const int lane = threadIdx.x & 63;
    const int wav  = threadIdx.x >> 6;
    const int j = lane & 15;
    const int q = lane >> 4;

    float bias[32];
#pragma unroll
    for (int mt = 0; mt < 8; ++mt)
#pragma unroll
        for (int r = 0; r < 4; ++r) bias[mt * 4 + r] = b_msg[mt * 16 + q * 4 + r];
    __syncthreads();

    const int e0w = blockIdx.x * 256 + wav * 64;
    float carry[32];
    int carry_d = -1;

#pragma unroll 1
    for (int g = 0; g < 4; ++g) {
        const int e = e0w + g * 16 + j;
        const i32x4 m = meta[e];
        const int p = m[0];
        const int d = m[2];
        const int sp = min(max(m[1], 0), N_NODES - 1);
        const float invc = 1.0f / (float)cnt[d];

        frag8 bfr[6];
        const float* nrow = node_emb + (size_t)sp * D_NODE;
#pragma unroll
        for (int kc = 0; kc < 4; ++kc) {
            float4 a = *(const float4*)&nrow[kc * 32 + q * 8];
            float4 c = *(const float4*)&nrow[kc * 32 + q * 8 + 4];
            bfr[kc] = pack8(a, c);
        }
        const float* erow = edge_emb + (size_t)p * D_EDGE;
#pragma unroll
        for (int kc = 0; kc < 2; ++kc) {
            float4 a = *(const float4*)&erow[kc * 32 + q * 8];
            float4 c = *(const float4*)&erow[kc * 32 + q * 8 + 4];
            bfr[4 + kc] = pack8(a, c);
        }

        facc acc[8];
#pragma unroll
        for (int mt = 0; mt < 8; ++mt) { facc z = {0.f, 0.f, 0.f, 0.f}; acc[mt] = z; }

#pragma unroll
        for (int mt = 0; mt < 8; ++mt) {
            const unsigned short* wrow = &sW[(mt * 16 + j) * K1];
            const int rs = j & 7;
#pragma unroll
            for (int kc = 0; kc < 6; ++kc) {
                frag8 a = *(const frag8*)&wrow[((kc * 4 + q) ^ rs) * 8];
                acc[mt] = __builtin_amdgcn_mfma_f32_16x16x32_bf16(a, bfr[kc], acc[mt], 0, 0, 0);
            }
        }

        float v[32];
#pragma unroll
        for (int mt = 0; mt < 8; ++mt)
#pragma unroll
            for (int r = 0; r < 4; ++r) {
                float t = acc[mt][r] + bias[mt * 4 + r];
                v[mt * 4 + r] = fmaxf(t, 0.f) * invc;
            }

        int dprev = __shfl_up(d, 1, 16);
        int head = (j == 0 || d != dprev) ? 1 : 0;
        int seg = head;
#pragma unroll
        for (int s = 1; s < 16; s <<= 1) { int t = __shfl_up(seg, s, 16); if (j >= s) seg += t; }
        int sg1 = __shfl_up(seg, 1, 16);
        int sg2 = __shfl_up(seg, 2, 16);
        int sg4 = __shfl_up(seg, 4, 16);
        int sg8 = __shfl_up(seg, 8, 16);
        bool ok1 = (j >= 1) && (sg1 == seg);
        bool ok2 = (j >= 2) && (sg2 == seg);
        bool ok4 = (j >= 4) && (sg4 == seg);
        bool ok8 = (j >= 8) && (sg8 == seg);

#pragma unroll
        for (int i = 0; i < 32; ++i) { float t = __shfl_up(v[i], 1, 16); if (ok1) v[i] += t; }
#pragma unroll
        for (int i = 0; i < 32; ++i) { float t = __shfl_up(v[i], 2, 16); if (ok2) v[i] += t; }
#pragma unroll
        for (int i = 0; i < 32; ++i) { float t = __shfl_up(v[i], 4, 16); if (ok4) v[i] += t; }
#pragma unroll
        for (int i = 0; i < 32; ++i) { float t = __shfl_up(v[i], 8, 16); if (ok8) v[i] += t; }

        int d0 = __shfl(d, 0, 16);
        if (g > 0) {
            if (d0 != carry_d) {
                if (j == 0) {
                    float* mrow = mean + (size_t)carry_d * D_MSG;
#pragma unroll
                    for (int mt = 0; mt < 8; ++mt)
#pragma unroll
                        for (int r = 0; r < 4; ++r)
                            atomicAdd(&mrow[mt * 16 + q * 4 + r], carry[mt * 4 + r]);
                }
            } else if (seg == 1) {
#pragma unroll
                for (int i = 0; i < 32; ++i) v[i] += carry[i];
            }
        }

#pragma unroll
        for (int i = 0; i < 32; ++i) carry[i] = __shfl(v[i], 15, 16);
        carry_d = __shfl(d, 15, 16);

        int dnext = __shfl_down(d, 1, 16);
        bool tail = (j < 15) ? (dnext != d) : (g == 3);
        if (tail) {
            float* mrow = mean + (size_t)d * D_MSG;
#pragma unroll
            for (int mt = 0; mt < 8; ++mt)
#pragma unroll
                for (int r = 0; r < 4; ++r)
                    atomicAdd(&mrow[mt * 16 + q * 4 + r], v[mt * 4 + r]);
        }
    }
}

__global__ __launch_bounds__(256) void node_kernel_fb(
    const float* __restrict__ node_emb, const float* __restrict__ mean,
    const unsigned short* __restrict__ WtU, const float* __restrict__ b_upd,
    float* __restrict__ out)
{
    __shared__ unsigned short sW[128 * K2];

    for (int idx = threadIdx.x; idx < 128 * 32; idx += 256) {
        int o = idx >> 5, ch = idx & 31;
        *(uint4*)&sW[o * K2 + (ch ^ (o & 7)) * 8] = *(const uint4*)&WtU[o * K2 + ch * 8];
    }

    const int lane = threadIdx.x & 63;
    const int wav  = threadIdx.x >> 6;
    const int j = lane & 15;
    const int q = lane >> 4;

    float bias[32];
#pragma unroll
    for (int mt = 0; mt < 8; ++mt)
#pragma unroll
        for (int r = 0; r < 4; ++r) bias[mt * 4 + r] = b_upd[mt * 16 + q * 4 + r];
    __syncthreads();

    const int n0w = blockIdx.x * 256 + wav * 64;

#pragma unroll 1
    for (int g = 0; g < 4; ++g) {
        const int n = n0w + g * 16 + j;
        const bool valid = (n < N_NODES);
        const size_t nn = valid ? (size_t)n : 0;

        frag8 bfr[8];
        const float* nrow = node_emb + nn * D_NODE;
#pragma unroll
        for (int kc = 0; kc < 4; ++kc) {
            float4 a = *(const float4*)&nrow[kc * 32 + q * 8];
            float4 c = *(const float4*)&nrow[kc * 32 + q * 8 + 4];
            bfr[kc] = pack8(a, c);
        }
        const float* mrow = mean + nn * D_MSG;
#pragma unroll
        for (int kc = 0; kc < 4; ++kc) {
            float4 a = *(const float4*)&mrow[kc * 32 + q * 8];
            float4 c = *(const float4*)&mrow[kc * 32 + q * 8 + 4];
            bfr[4 + kc] = pack8(a, c);
        }

        facc acc[8];
#pragma unroll
        for (int mt = 0; mt < 8; ++mt) { facc z = {0.f, 0.f, 0.f, 0.f}; acc[mt] = z; }

#pragma unroll
        for (int mt = 0; mt < 8; ++mt) {
            const unsigned short* wrow = &sW[(mt * 16 + j) * K2];
            const int rs = j & 7;
#pragma unroll
            for (int kc = 0; kc < 8; ++kc) {
                frag8 a = *(const frag8*)&wrow[((kc * 4 + q) ^ rs) * 8];
                acc[mt] = __builtin_amdgcn_mfma_f32_16x16x32_bf16(a, bfr[kc], acc[mt], 0, 0, 0);
            }
        }

        if (valid) {
            float* orow = out + (size_t)n * D_OUT;
#pragma unroll
            for (int mt = 0; mt < 8; ++mt)
#pragma unroll
                for (int r = 0; r < 4; ++r)
                    orow[mt * 16 + q * 4 + r] = fmaxf(acc[mt][r] + bias[mt * 4 + r], 0.f);
        }
    }
}

extern "C" void kernel_launch(void* const* d_in, const int* in_sizes, int n_in,
                              void* d_out, int out_size, void* d_ws, size_t ws_size,
                              hipStream_t stream) {
    const float* node_emb = (const float*)d_in[0];
    const int*   edge_idx = (const int*)d_in[1];
    const float* edge_emb = (const float*)d_in[2];
    const float* W_msg    = (const float*)d_in[3];
    const float* b_msg    = (const float*)d_in[4];
    const float* W_upd    = (const float*)d_in[5];
    const float* b_upd    = (const float*)d_in[6];
    float* out = (float*)d_out;

    const int* src = edge_idx;
    const int* dst = edge_idx + N_EDGES;

    char* W = (char*)d_ws;

    if (ws_size >= 104000000ULL) {
        // ---- FAST PATH ----
        unsigned short* meanB = (unsigned short*)(W + 0);         // 25,600,000
        int* cnt     = (int*)(W + 25600000);                      //    400,000
        int* cursor  = (int*)(W + 26000000);                      //    400,000
        int* base    = (int*)(W + 26400000);                      //    400,000
        int* part    = (int*)(W + 26800000);                      //        512
        i32x4* meta  = (i32x4*)(W + 26800512);                    // 25,600,000
        unsigned short* WtM   = (unsigned short*)(W + 52400512);  //     49,152
        unsigned short* WtU   = (unsigned short*)(W + 52449664);  //     65,536
        unsigned short* nodeB = (unsigned short*)(W + 52515200);  // 25,600,000
        float* spill = (float*)(W + 78115200);                    //  25,600,000

        // zero only cnt + cursor
        hipMemsetAsync(W + 25600000, 0, 800000, stream);

        prep_all_kernel<<<2048, 256, 0, stream>>>(W_msg, W_upd, node_emb, dst,
                                                  (unsigned int*)nodeB, cnt, WtM, WtU);
        scan_blocks<<<NSB, 1024, 0, stream>>>(cnt, base, part);
        scan_add<<<NSB, 1024, 0, stream>>>(base, part);
        scatter_kernel<<<1024, 256, 0, stream>>>(dst, src, base, cursor, meta);
        msg_fused_kernel<<<2048, 256, 0, stream>>>(nodeB, meta, edge_emb,
                                                   WtM, b_msg, base, cnt,
                                                   (unsigned int*)meanB, spill);
        cleanup_kernel<<<1600, 256, 0, stream>>>(meta, base, cnt, spill,
                                                 (unsigned int*)meanB);
        node_gemm_kernel<<<782, 256, 0, stream>>>(nodeB, meanB, WtU, b_upd, out);
    } else {
        // ---- FALLBACK ----
        float* mean  = (float*)W;                               // 51,200,000
        int* cnt     = (int*)(W + 51200000);
        int* cursor  = (int*)(W + 51600000);
        int* base    = (int*)(W + 52000000);
        int* part    = (int*)(W + 52400000);
        i32x4* meta  = (i32x4*)(W + 52400512);                  // 25,600,000
        unsigned short* WtM = (unsigned short*)(W + 78000512);
        unsigned short* WtU = (unsigned short*)(W + 78049664);

        hipMemsetAsync(d_ws, 0, 52000000, stream);

        prep_w_kernel<<<224, 256, 0, stream>>>(W_msg, W_upd, WtM, WtU);
        hist_kernel<<<1024, 256, 0, stream>>>(dst, cnt);
        scan_blocks<<<NSB, 1024, 0, stream>>>(cnt, base, part);
        scan_add<<<NSB, 1024, 0, stream>>>(base, part);
        scatter_kernel<<<1024, 256, 0, stream>>>(dst, src, base, cursor, meta);
        msg_agg_kernel_fb<<<6250, 256, 0, stream>>>(node_emb, meta, edge_emb, WtM,
                                                    b_msg, cnt, mean);
        node_kernel_fb<<<391, 256, 0, stream>>>(node_emb, mean, WtU, b_upd, out);
    }
}

// Round 13
// 568.722 us; speedup vs baseline: 1.0905x; 1.0039x over previous
//
#include <hip/hip_runtime.h>
#include <hip/hip_bf16.h>

#define N_NODES 100000
#define N_EDGES 1600000
#define D_NODE 128
#define D_EDGE 64
#define D_MSG 128
#define K1 192   // NODE_DIM + EDGE_DIM
#define K2 256   // NODE_DIM + MSG_DIM
#define D_OUT 128
#define NSB 98   // scan blocks: ceil(100000/1024)
#define TILE 64
#define NT (N_EDGES / TILE)   // 25000 exact

using frag8 = __attribute__((ext_vector_type(8))) short;   // 8 bf16 (4 VGPRs)
using facc  = __attribute__((ext_vector_type(4))) float;   // 4 f32 acc
typedef int   i32x4 __attribute__((ext_vector_type(4)));
typedef float f32x2 __attribute__((ext_vector_type(2)));
typedef float f32x4v __attribute__((ext_vector_type(4)));

static __device__ __forceinline__ unsigned short f2bf(float f) {
    unsigned int u = __float_as_uint(f);
    u = u + 0x7fffu + ((u >> 16) & 1u);   // RNE
    return (unsigned short)(u >> 16);
}
static __device__ __forceinline__ float bflo(unsigned int u) { return __uint_as_float(u << 16); }
static __device__ __forceinline__ float bfhi(unsigned int u) { return __uint_as_float(u & 0xffff0000u); }

union F8 { unsigned short s[8]; frag8 f; uint4 u4; };

static __device__ __forceinline__ frag8 pack8(float4 a, float4 b) {
    F8 u;
    u.s[0] = f2bf(a.x); u.s[1] = f2bf(a.y); u.s[2] = f2bf(a.z); u.s[3] = f2bf(a.w);
    u.s[4] = f2bf(b.x); u.s[5] = f2bf(b.y); u.s[6] = f2bf(b.z); u.s[7] = f2bf(b.w);
    return u.f;
}

// ---------------------------------------------------------------------------
// prep_all: W transpose->bf16, node_emb->bf16 (float4 vectorized), dst hist.
// ---------------------------------------------------------------------------
__global__ void prep_all_kernel(const float* __restrict__ Wm, const float* __restrict__ Wu,
                                const float* __restrict__ node_emb, const int* __restrict__ dst,
                                unsigned int* __restrict__ nodeB32, int* __restrict__ cnt,
                                unsigned short* __restrict__ WtM, unsigned short* __restrict__ WtU) {
    int idx0 = blockIdx.x * blockDim.x + threadIdx.x;
    int stride = gridDim.x * blockDim.x;
    for (int idx = idx0; idx < 128 * K1; idx += stride) {
        int o = idx / K1, k = idx - o * K1;
        WtM[idx] = f2bf(Wm[k * D_MSG + o]);
    }
    for (int idx = idx0; idx < 128 * K2; idx += stride) {
        int o = idx >> 8, k = idx & 255;
        WtU[idx] = f2bf(Wu[k * D_OUT + o]);
    }
    const int total = N_NODES * 32;   // float4 quads
    for (int i = idx0; i < total; i += stride) {
        float4 v = *(const float4*)&node_emb[(size_t)i * 4];
        uint2 w;
        w.x = (unsigned)f2bf(v.x) | ((unsigned)f2bf(v.y) << 16);
        w.y = (unsigned)f2bf(v.z) | ((unsigned)f2bf(v.w) << 16);
        *(uint2*)&nodeB32[(size_t)i * 2] = w;
    }
    for (int e = idx0; e < N_EDGES; e += stride) {
        int d = min(max(dst[e], 0), N_NODES - 1);
        atomicAdd(&cnt[d], 1);
    }
}

__global__ __launch_bounds__(1024) void scan_blocks(const int* __restrict__ cnt,
                                                    int* __restrict__ base,
                                                    int* __restrict__ part) {
    __shared__ int sh[1024];
    int i = blockIdx.x * 1024 + threadIdx.x;
    int c = (i < N_NODES) ? cnt[i] : 0;
    sh[threadIdx.x] = c;
    __syncthreads();
    for (int s = 1; s < 1024; s <<= 1) {
        int t = (threadIdx.x >= s) ? sh[threadIdx.x - s] : 0;
        __syncthreads();
        sh[threadIdx.x] += t;
        __syncthreads();
    }
    if (i < N_NODES) base[i] = sh[threadIdx.x] - c;   // exclusive within block
    if (threadIdx.x == 1023) part[blockIdx.x] = sh[1023];   // raw block sum
}

// scan_add: computes this block's partial-prefix in-wave
__global__ __launch_bounds__(1024) void scan_add(int* __restrict__ base, const int* __restrict__ part) {
    __shared__ int soff;
    if (threadIdx.x < 64) {
        int l = threadIdx.x;
        int v = 0;
        if (l < blockIdx.x) v += part[l];
        if (l + 64 < blockIdx.x) v += part[l + 64];
#pragma unroll
        for (int s = 32; s; s >>= 1) v += __shfl_down(v, s, 64);
        if (l == 0) soff = v;
    }
    __syncthreads();
    int i = blockIdx.x * 1024 + threadIdx.x;
    if (i < N_NODES) base[i] += soff;
}

// ---------------------------------------------------------------------------
// scatter: bins edges by dst; 4 edges/thread (int4 index loads), one packed
// int4 nt-store per edge. meta[pos] = {orig_e, src[e], d, 0}
// ---------------------------------------------------------------------------
__global__ void scatter_kernel(const int* __restrict__ dst, const int* __restrict__ src,
                               const int* __restrict__ base, int* __restrict__ cursor,
                               i32x4* __restrict__ meta) {
    int idx0 = blockIdx.x * blockDim.x + threadIdx.x;
    int stride = gridDim.x * blockDim.x;
    const int nQuads = N_EDGES / 4;   // 400000 exact
    for (int qd = idx0; qd < nQuads; qd += stride) {
        i32x4 s4 = *(const i32x4*)&src[qd * 4];
        i32x4 d4 = *(const i32x4*)&dst[qd * 4];
#pragma unroll
        for (int k = 0; k < 4; ++k) {
            int d = min(max(d4[k], 0), N_NODES - 1);
            int pos = base[d] + atomicAdd(&cursor[d], 1);
            i32x4 m; m[0] = qd * 4 + k; m[1] = s4[k]; m[2] = d; m[3] = 0;
            __builtin_nontemporal_store(m, &meta[pos]);
        }
    }
}

// ---------------------------------------------------------------------------
// FUSED Phase A: per 64-edge tile: msg GEMM (W in regs, inputs staged in
// XOR-swizzled LDS) -> msg tile in LDS -> in-block per-node mean.
// TWO barriers per iteration (r13): barrier (a) removed — sIn writes are
// fenced by (c) (GEMM reads done), sMsg mean-read vs next epilogue-write
// is fenced by (b). Mean phase of tile t overlaps staging of tile t+1.
// ---------------------------------------------------------------------------
__global__ __launch_bounds__(256, 3) void msg_fused_kernel(
    const unsigned short* __restrict__ nodeB, const i32x4* __restrict__ meta,
    const float* __restrict__ edge_emb, const unsigned short* __restrict__ WtM,
    const float* __restrict__ b_msg, const int* __restrict__ base,
    const int* __restrict__ cnt, unsigned int* __restrict__ meanB32,
    float* __restrict__ spill)
{
    __shared__ unsigned short sIn[TILE][192];    // 24576 B; 16B chunks XOR row&7
    __shared__ unsigned short sMsg[TILE][128];   // 16384 B; 8B chunks XOR row&7

    const int lane = threadIdx.x & 63;
    const int wav  = threadIdx.x >> 6;
    const int j = lane & 15;
    const int q = lane >> 4;

    // W slice (out rows 32*wav .. 32*wav+31) in registers
    frag8 wfr[2][6];
#pragma unroll
    for (int m2 = 0; m2 < 2; ++m2) {
        const unsigned short* wrow = WtM + ((wav * 2 + m2) * 16 + j) * K1;
#pragma unroll
        for (int kc = 0; kc < 6; ++kc)
            wfr[m2][kc] = *(const frag8*)&wrow[(kc * 4 + q) * 8];
    }
    float bias[2][4];
#pragma unroll
    for (int m2 = 0; m2 < 2; ++m2)
#pragma unroll
        for (int r = 0; r < 4; ++r) bias[m2][r] = b_msg[(wav * 2 + m2) * 16 + q * 4 + r];

    // staging role: thread t covers edge row eL = t>>2, quarter qt = t&3
    const int eL = threadIdx.x >> 2;
    const int qt = threadIdx.x & 3;
    const int swz = eL & 7;

    uint4  nst[4];    // node part: 64B bf16 (cached gather)
    float4 est[4];    // edge part: 64B f32 (cached)

    const int t0 = blockIdx.x;

    // prologue: issue loads for tile t0
    {
        const int e = t0 * TILE + eL;
        const i32x4 m = meta[e];
        const int sp = min(max(m[1], 0), N_NODES - 1);
        const unsigned short* nrow = nodeB + (size_t)sp * D_NODE + qt * 32;
#pragma unroll
        for (int i = 0; i < 4; ++i) nst[i] = *(const uint4*)&nrow[i * 8];
        const float* erow = edge_emb + (size_t)m[0] * D_EDGE + qt * 16;
#pragma unroll
        for (int i = 0; i < 4; ++i) est[i] = *(const float4*)&erow[i * 4];
    }

#pragma unroll 1
    for (int t = t0; t < NT; t += gridDim.x) {
        const int e0 = t * TILE;

        // write staged tile into sIn (XOR-swizzled 16B chunks).
        // Safe without a leading barrier: GEMM reads of sIn (prev iter)
        // completed before barrier (c) of the previous iteration.
        {
            unsigned short* drow = &sIn[eL][0];
#pragma unroll
            for (int i = 0; i < 4; ++i)
                *(uint4*)&drow[((4 * qt + i) ^ swz) * 8] = nst[i];
#pragma unroll
            for (int h = 0; h < 2; ++h) {
                F8 u;
                u.f = pack8(est[h * 2], est[h * 2 + 1]);
                *(uint4*)&drow[((16 + 2 * qt + h) ^ swz) * 8] = u.u4;
            }
        }

        // issue next tile's loads BEFORE the barrier (latency overlaps wait)
        const int tn = t + gridDim.x;
        if (tn < NT) {
            const int e = tn * TILE + eL;
            const i32x4 m = meta[e];
            const int sp = min(max(m[1], 0), N_NODES - 1);
            const unsigned short* nrow = nodeB + (size_t)sp * D_NODE + qt * 32;
#pragma unroll
            for (int i = 0; i < 4; ++i) nst[i] = *(const uint4*)&nrow[i * 8];
            const float* erow = edge_emb + (size_t)m[0] * D_EDGE + qt * 16;
#pragma unroll
            for (int i = 0; i < 4; ++i) est[i] = *(const float4*)&erow[i * 4];
        }

        __syncthreads();   // (b) sIn ready; also fences prev mean vs epilogue

        // GEMM: wave computes outs 32*wav..+31 for all 64 edges
        facc acc[2][4];
#pragma unroll
        for (int m2 = 0; m2 < 2; ++m2)
#pragma unroll
            for (int eg = 0; eg < 4; ++eg) { facc z = {0.f,0.f,0.f,0.f}; acc[m2][eg] = z; }

        const int rsw = j & 7;
#pragma unroll
        for (int eg = 0; eg < 4; ++eg) {
            const unsigned short* irow = &sIn[eg * 16 + j][0];
#pragma unroll
            for (int kc = 0; kc < 6; ++kc) {
                frag8 b = *(const frag8*)&irow[((4 * kc + q) ^ rsw) * 8];
                acc[0][eg] = __builtin_amdgcn_mfma_f32_16x16x32_bf16(wfr[0][kc], b, acc[0][eg], 0, 0, 0);
                acc[1][eg] = __builtin_amdgcn_mfma_f32_16x16x32_bf16(wfr[1][kc], b, acc[1][eg], 0, 0, 0);
            }
        }

        // epilogue: bias+relu+cvt bf16 -> sMsg (8B chunks XOR row&7)
#pragma unroll
        for (int eg = 0; eg < 4; ++eg) {
            unsigned short* mrow = &sMsg[eg * 16 + j][0];
#pragma unroll
            for (int m2 = 0; m2 < 2; ++m2) {
                float v0 = fmaxf(acc[m2][eg][0] + bias[m2][0], 0.f);
                float v1 = fmaxf(acc[m2][eg][1] + bias[m2][1], 0.f);
                float v2 = fmaxf(acc[m2][eg][2] + bias[m2][2], 0.f);
                float v3 = fmaxf(acc[m2][eg][3] + bias[m2][3], 0.f);
                uint2 w;
                w.x = (unsigned)f2bf(v0) | ((unsigned)f2bf(v1) << 16);
                w.y = (unsigned)f2bf(v2) | ((unsigned)f2bf(v3) << 16);
                int c64 = wav * 8 + m2 * 4 + q;        // u64 index 0..31
                *(uint2*)&mrow[(c64 ^ rsw) * 4] = w;
            }
        }
        __syncthreads();   // (c) sMsg ready; GEMM reads of sIn complete

        // in-block mean finish: wave handles nodes d_lo+wav, +4, ...
        // (overlaps next iteration's sIn staging across waves)
        const int d_lo = ((const int*)&meta[e0])[2];
        const int d_hi = ((const int*)&meta[e0 + TILE - 1])[2];
        for (int n = d_lo + wav; n <= d_hi; n += 4) {
            const int b = base[n];
            const int c = cnt[n];
            const int lo = max(b - e0, 0);
            const int hi = min(b + c - e0, TILE);
            float s0 = 0.f, s1 = 0.f;
            for (int r = lo; r < hi; ++r) {
                const unsigned* mr = (const unsigned*)&sMsg[r][0];
                unsigned u = mr[(((lane >> 1) ^ (r & 7)) << 1) | (lane & 1)];
                s0 += bflo(u); s1 += bfhi(u);
            }
            const float inv = 1.0f / fmaxf((float)c, 1.0f);
            s0 *= inv; s1 *= inv;
            if (b >= e0 && b + c <= e0 + TILE) {
                // interior: exclusive owner, direct bf16 mean row write (nt)
                unsigned int w = (unsigned)f2bf(s0) | ((unsigned)f2bf(s1) << 16);
                __builtin_nontemporal_store(w, &meanB32[(size_t)n * 64 + lane]);
            } else {
                // non-interior: deterministic f32 spill slot (NO atomics, nt)
                int slot = (n == d_lo) ? 0 : 1;
                f32x2 w; w[0] = s0; w[1] = s1;
                __builtin_nontemporal_store(
                    w, (f32x2*)(spill + ((size_t)(t * 2 + slot)) * D_MSG + lane * 2));
            }
        }
    }
}

// ---------------------------------------------------------------------------
// cleanup: finish boundary nodes (sum their per-tile spill rows) and write
// zero rows for degree-0 nodes. Grid-stride; nt loads on spill stream.
// ---------------------------------------------------------------------------
__global__ __launch_bounds__(256) void cleanup_kernel(
    const i32x4* __restrict__ meta, const int* __restrict__ base,
    const int* __restrict__ cnt, const float* __restrict__ spill,
    unsigned int* __restrict__ meanB32)
{
    const int wav = threadIdx.x >> 6;
    const int lane = threadIdx.x & 63;
    const int nstride = gridDim.x * 4;
    for (int n = blockIdx.x * 4 + wav; n < N_NODES; n += nstride) {
        const int c = cnt[n];
        float s0 = 0.f, s1 = 0.f;
        if (c > 0) {
            const int b = base[n];
            const int t0 = b >> 6, t1 = (b + c - 1) >> 6;
            if (t0 == t1) continue;   // interior: already written by msg_fused
            for (int t = t0; t <= t1; ++t) {
                const int slot = (((const int*)&meta[t * TILE])[2] == n) ? 0 : 1;
                f32x2 v = __builtin_nontemporal_load(
                    (const f32x2*)(spill + ((size_t)(t * 2 + slot)) * D_MSG + lane * 2));
                s0 += v[0]; s1 += v[1];
            }
        }
        meanB32[(size_t)n * 64 + lane] = (unsigned)f2bf(s0) | ((unsigned)f2bf(s1) << 16);
    }
}

// ---------------------------------------------------------------------------
// Phase C: node GEMM, all-bf16 fragment loads; nt-stores for write-once out.
// ---------------------------------------------------------------------------
__global__ __launch_bounds__(256) void node_gemm_kernel(
    const unsigned short* __restrict__ nodeB, const unsigned short* __restrict__ meanB,
    const unsigned short* __restrict__ WtU, const float* __restrict__ b_upd,
    float* __restrict__ out)
{
    __shared__ unsigned short sW[128 * K2];   // 65536 B

    for (int idx = threadIdx.x; idx < 128 * 32; idx += 256) {
        int o = idx >> 5, ch = idx & 31;
        *(uint4*)&sW[o * K2 + (ch ^ (o & 7)) * 8] = *(const uint4*)&WtU[o * K2 + ch * 8];
    }

    const int lane = threadIdx.x & 63;
    const int wav  = threadIdx.x >> 6;
    const int j = lane & 15;
    const int q = lane >> 4;
    const int rs = j & 7;

    float bias[32];
#pragma unroll
    for (int mt = 0; mt < 8; ++mt)
#pragma unroll
        for (int r = 0; r < 4; ++r) bias[mt * 4 + r] = b_upd[mt * 16 + q * 4 + r];
    __syncthreads();

    const int n0w = blockIdx.x * 128 + wav * 32;

#pragma unroll 1
    for (int g = 0; g < 2; ++g) {
        const int n = n0w + g * 16 + j;
        const bool valid = (n < N_NODES);
        const size_t nn = valid ? (size_t)n : 0;

        frag8 bfr[8];
        const unsigned short* nrow = nodeB + nn * D_NODE;
#pragma unroll
        for (int kc = 0; kc < 4; ++kc)
            bfr[kc] = *(const frag8*)&nrow[kc * 32 + q * 8];
        const unsigned short* mrow = meanB + nn * D_MSG;
#pragma unroll
        for (int kc = 0; kc < 4; ++kc)
            bfr[4 + kc] = *(const frag8*)&mrow[kc * 32 + q * 8];

        facc acc[8];
#pragma unroll
        for (int mt = 0; mt < 8; ++mt) { facc z = {0.f, 0.f, 0.f, 0.f}; acc[mt] = z; }

#pragma unroll
        for (int mt = 0; mt < 8; ++mt) {
            const unsigned short* wrow = &sW[(mt * 16 + j) * K2];
#pragma unroll
            for (int kc = 0; kc < 8; ++kc) {
                frag8 a = *(const frag8*)&wrow[((kc * 4 + q) ^ rs) * 8];
                acc[mt] = __builtin_amdgcn_mfma_f32_16x16x32_bf16(a, bfr[kc], acc[mt], 0, 0, 0);
            }
        }

        if (valid) {
            float* orow = out + (size_t)n * D_OUT;
#pragma unroll
            for (int mt = 0; mt < 8; ++mt) {
                f32x4v w;
                w[0] = fmaxf(acc[mt][0] + bias[mt * 4 + 0], 0.f);
                w[1] = fmaxf(acc[mt][1] + bias[mt * 4 + 1], 0.f);
                w[2] = fmaxf(acc[mt][2] + bias[mt * 4 + 2], 0.f);
                w[3] = fmaxf(acc[mt][3] + bias[mt * 4 + 3], 0.f);
                __builtin_nontemporal_store(w, (f32x4v*)&orow[mt * 16 + q * 4]);
            }
        }
    }
}

// ===========================================================================
// FALLBACK PATH (round-3 style, meta-packed): fused msg+aggregate if ws small.
// ===========================================================================
__global__ void prep_w_kernel(const float* __restrict__ Wm, const float* __restrict__ Wu,
                              unsigned short* __restrict__ WtM, unsigned short* __restrict__ WtU) {
    int idx0 = blockIdx.x * blockDim.x + threadIdx.x;
    int stride = gridDim.x * blockDim.x;
    for (int idx = idx0; idx < 128 * K1; idx += stride) {
        int o = idx / K1, k = idx - o * K1;
        WtM[idx] = f2bf(Wm[k * D_MSG + o]);
    }
    for (int idx = idx0; idx < 128 * K2; idx += stride) {
        int o = idx >> 8, k = idx & 255;
        WtU[idx] = f2bf(Wu[k * D_OUT + o]);
    }
}

__global__ void hist_kernel(const int* __restrict__ dst, int* __restrict__ cnt) {
    int idx0 = blockIdx.x * blockDim.x + threadIdx.x;
    int stride = gridDim.x * blockDim.x;
    for (int e = idx0; e < N_EDGES; e += stride) {
        int d = min(max(dst[e], 0), N_NODES - 1);
        atomicAdd(&cnt[d], 1);
    }
}

__global__ __launch_bounds__(256) void msg_agg_kernel_fb(
    const float* __restrict__ node_emb, const i32x4* __restrict__ meta,
    const float* __restrict__ edge_emb, const unsigned short* __restrict__ WtM,
    const float* __restrict__ b_msg, const int* __restrict__ cnt,
    float* __restrict__ mean)
{
    __shared__ unsigned short sW[128 * K1];

    for (int idx = threadIdx.x; idx < 128 * 24; idx += 256) {
        int o = idx / 24, ch = idx % 24;
        *(uint4*)&sW[o * K1 + (ch ^ (o & 7)) * 8] = *(const uint4*)&WtM[o * K1 + ch * 8];
    }

    const int lane = threadIdx.x & 63;
    const int wav  = threadIdx.x >> 6;
    const int j = lane & 15;
    const int q = lane >> 4;

    float bias[32];
#pragma unroll
    for (int mt = 0; mt < 8; ++mt)
#pragma unroll
        for (int r = 0; r < 4; ++r) bias[mt * 4 + r] = b_msg[mt * 16 + q * 4 + r];
    __syncthreads();

    const int e0w = blockIdx.x * 256 + wav * 64;
    float carry[32];
    int carry_d = -1;

#pragma unroll 1
    for (int g = 0; g < 4; ++g) {
        const int e = e0w + g * 16 + j;
        const i32x4 m = meta[e];
        const int p = m[0];
        const int d = m[2];
        const int sp = min(max(m[1], 0), N_NODES - 1);
        const float invc = 1.0f / (float)cnt[d];

        frag8 bfr[6];
        const float* nrow = node_emb + (size_t)sp * D_NODE;
#pragma unroll
        for (int kc = 0; kc < 4; ++kc) {
            float4 a = *(const float4*)&nrow[kc * 32 + q * 8];
            float4 c = *(const float4*)&nrow[kc * 32 + q * 8 + 4];
            bfr[kc] = pack8(a, c);
        }
        const float* erow = edge_emb + (size_t)p * D_EDGE;
#pragma unroll
        for (int kc = 0; kc < 2; ++kc) {
            float4 a = *(const float4*)&erow[kc * 32 + q * 8];
            float4 c = *(const float4*)&erow[kc * 32 + q * 8 + 4];
            bfr[4 + kc] = pack8(a, c);
        }

        facc acc[8];
#pragma unroll
        for (int mt = 0; mt < 8; ++mt) { facc z = {0.f, 0.f, 0.f, 0.f}; acc[mt] = z; }

#pragma unroll
        for (int mt = 0; mt < 8; ++mt) {
            const unsigned short* wrow = &sW[(mt * 16 + j) * K1];
            const int rs = j & 7;
#pragma unroll
            for (int kc = 0; kc < 6; ++kc) {
                frag8 a = *(const frag8*)&wrow[((kc * 4 + q) ^ rs) * 8];
                acc[mt] = __builtin_amdgcn_mfma_f32_16x16x32_bf16(a, bfr[kc], acc[mt], 0, 0, 0);
            }
        }

        float v[32];
#pragma unroll
        for (int mt = 0; mt < 8; ++mt)
#pragma unroll
            for (int r = 0; r < 4; ++r) {
                float t = acc[mt][r] + bias[mt * 4 + r];
                v[mt * 4 + r] = fmaxf(t, 0.f) * invc;
            }

        int dprev = __shfl_up(d, 1, 16);
        int head = (j == 0 || d != dprev) ? 1 : 0;
        int seg = head;
#pragma unroll
        for (int s = 1; s < 16; s <<= 1) { int t = __shfl_up(seg, s, 16); if (j >= s) seg += t; }
        int sg1 = __shfl_up(seg, 1, 16);
        int sg2 = __shfl_up(seg, 2, 16);
        int sg4 = __shfl_up(seg, 4, 16);
        int sg8 = __shfl_up(seg, 8, 16);
        bool ok1 = (j >= 1) && (sg1 == seg);
        bool ok2 = (j >= 2) && (sg2 == seg);
        bool ok4 = (j >= 4) && (sg4 == seg);
        bool ok8 = (j >= 8) && (sg8 == seg);

#pragma unroll
        for (int i = 0; i < 32; ++i) { float t = __shfl_up(v[i], 1, 16); if (ok1) v[i] += t; }
#pragma unroll
        for (int i = 0; i < 32; ++i) { float t = __shfl_up(v[i], 2, 16); if (ok2) v[i] += t; }
#pragma unroll
        for (int i = 0; i < 32; ++i) { float t = __shfl_up(v[i], 4, 16); if (ok4) v[i] += t; }
#pragma unroll
        for (int i = 0; i < 32; ++i) { float t = __shfl_up(v[i], 8, 16); if (ok8) v[i] += t; }

        int d0 = __shfl(d, 0, 16);
        if (g > 0) {
            if (d0 != carry_d) {
                if (j == 0) {
                    float* mrow = mean + (size_t)carry_d * D_MSG;
#pragma unroll
                    for (int mt = 0; mt < 8; ++mt)
#pragma unroll
                        for (int r = 0; r < 4; ++r)
                            atomicAdd(&mrow[mt * 16 + q * 4 + r], carry[mt * 4 + r]);
                }
            } else if (seg == 1) {
#pragma unroll
                for (int i = 0; i < 32; ++i) v[i] += carry[i];
            }
        }

#pragma unroll
        for (int i = 0; i < 32; ++i) carry[i] = __shfl(v[i], 15, 16);
        carry_d = __shfl(d, 15, 16);

        int dnext = __shfl_down(d, 1, 16);
        bool tail = (j < 15) ? (dnext != d) : (g == 3);
        if (tail) {
            float* mrow = mean + (size_t)d * D_MSG;
#pragma unroll
            for (int mt = 0; mt < 8; ++mt)
#pragma unroll
                for (int r = 0; r < 4; ++r)
                    atomicAdd(&mrow[mt * 16 + q * 4 + r], v[mt * 4 + r]);
        }
    }
}

__global__ __launch_bounds__(256) void node_kernel_fb(
    const float* __restrict__ node_emb, const float* __restrict__ mean,
    const unsigned short* __restrict__ WtU, const float* __restrict__ b_upd,
    float* __restrict__ out)
{
    __shared__ unsigned short sW[128 * K2];

    for (int idx = threadIdx.x; idx < 128 * 32; idx += 256) {
        int o = idx >> 5, ch = idx & 31;
        *(uint4*)&sW[o * K2 + (ch ^ (o & 7)) * 8] = *(const uint4*)&WtU[o * K2 + ch * 8];
    }

    const int lane = threadIdx.x & 63;
    const int wav  = threadIdx.x >> 6;
    const int j = lane & 15;
    const int q = lane >> 4;

    float bias[32];
#pragma unroll
    for (int mt = 0; mt < 8; ++mt)
#pragma unroll
        for (int r = 0; r < 4; ++r) bias[mt * 4 + r] = b_upd[mt * 16 + q * 4 + r];
    __syncthreads();

    const int n0w = blockIdx.x * 256 + wav * 64;

#pragma unroll 1
    for (int g = 0; g < 4; ++g) {
        const int n = n0w + g * 16 + j;
        const bool valid = (n < N_NODES);
        const size_t nn = valid ? (size_t)n : 0;

        frag8 bfr[8];
        const float* nrow = node_emb + nn * D_NODE;
#pragma unroll
        for (int kc = 0; kc < 4; ++kc) {
            float4 a = *(const float4*)&nrow[kc * 32 + q * 8];
            float4 c = *(const float4*)&nrow[kc * 32 + q * 8 + 4];
            bfr[kc] = pack8(a, c);
        }
        const float* mrow = mean + nn * D_MSG;
#pragma unroll
        for (int kc = 0; kc < 4; ++kc) {
            float4 a = *(const float4*)&mrow[kc * 32 + q * 8];
            float4 c = *(const float4*)&mrow[kc * 32 + q * 8 + 4];
            bfr[4 + kc] = pack8(a, c);
        }

        facc acc[8];
#pragma unroll
        for (int mt = 0; mt < 8; ++mt) { facc z = {0.f, 0.f, 0.f, 0.f}; acc[mt] = z; }

#pragma unroll
        for (int mt = 0; mt < 8; ++mt) {
            const unsigned short* wrow = &sW[(mt * 16 + j) * K2];
            const int rs = j & 7;
#pragma unroll
            for (int kc = 0; kc < 8; ++kc) {
                frag8 a = *(const frag8*)&wrow[((kc * 4 + q) ^ rs) * 8];
                acc[mt] = __builtin_amdgcn_mfma_f32_16x16x32_bf16(a, bfr[kc], acc[mt], 0, 0, 0);
            }
        }

        if (valid) {
            float* orow = out + (size_t)n * D_OUT;
#pragma unroll
            for (int mt = 0; mt < 8; ++mt)
#pragma unroll
                for (int r = 0; r < 4; ++r)
                    orow[mt * 16 + q * 4 + r] = fmaxf(acc[mt][r] + bias[mt * 4 + r], 0.f);
        }
    }
}

extern "C" void kernel_launch(void* const* d_in, const int* in_sizes, int n_in,
                              void* d_out, int out_size, void* d_ws, size_t ws_size,
                              hipStream_t stream) {
    const float* node_emb = (const float*)d_in[0];
    const int*   edge_idx = (const int*)d_in[1];
    const float* edge_emb = (const float*)d_in[2];
    const float* W_msg    = (const float*)d_in[3];
    const float* b_msg    = (const float*)d_in[4];
    const float* W_upd    = (const float*)d_in[5];
    const float* b_upd    = (const float*)d_in[6];
    float* out = (float*)d_out;

    const int* src = edge_idx;
    const int* dst = edge_idx + N_EDGES;

    char* W = (char*)d_ws;

    if (ws_size >= 104000000ULL) {
        // ---- FAST PATH ----
        unsigned short* meanB = (unsigned short*)(W + 0);         // 25,600,000
        int* cnt     = (int*)(W + 25600000);                      //    400,000
        int* cursor  = (int*)(W + 26000000);                      //    400,000
        int* base    = (int*)(W + 26400000);                      //    400,000
        int* part    = (int*)(W + 26800000);                      //        512
        i32x4* meta  = (i32x4*)(W + 26800512);                    // 25,600,000
        unsigned short* WtM   = (unsigned short*)(W + 52400512);  //     49,152
        unsigned short* WtU   = (unsigned short*)(W + 52449664);  //     65,536
        unsigned short* nodeB = (unsigned short*)(W + 52515200);  // 25,600,000
        float* spill = (float*)(W + 78115200);                    //  25,600,000

        // zero only cnt + cursor
        hipMemsetAsync(W + 25600000, 0, 800000, stream);

        prep_all_kernel<<<2048, 256, 0, stream>>>(W_msg, W_upd, node_emb, dst,
                                                  (unsigned int*)nodeB, cnt, WtM, WtU);
        scan_blocks<<<NSB, 1024, 0, stream>>>(cnt, base, part);
        scan_add<<<NSB, 1024, 0, stream>>>(base, part);
        scatter_kernel<<<1024, 256, 0, stream>>>(dst, src, base, cursor, meta);
        msg_fused_kernel<<<2048, 256, 0, stream>>>(nodeB, meta, edge_emb,
                                                   WtM, b_msg, base, cnt,
                                                   (unsigned int*)meanB, spill);
        cleanup_kernel<<<1600, 256, 0, stream>>>(meta, base, cnt, spill,
                                                 (unsigned int*)meanB);
        node_gemm_kernel<<<782, 256, 0, stream>>>(nodeB, meanB, WtU, b_upd, out);
    } else {
        // ---- FALLBACK ----
        float* mean  = (float*)W;                               // 51,200,000
        int* cnt     = (int*)(W + 51200000);
        int* cursor  = (int*)(W + 51600000);
        int* base    = (int*)(W + 52000000);
        int* part    = (int*)(W + 52400000);
        i32x4* meta  = (i32x4*)(W + 52400512);                  // 25,600,000
        unsigned short* WtM = (unsigned short*)(W + 78000512);
        unsigned short* WtU = (unsigned short*)(W + 78049664);

        hipMemsetAsync(d_ws, 0, 52000000, stream);

        prep_w_kernel<<<224, 256, 0, stream>>>(W_msg, W_upd, WtM, WtU);
        hist_kernel<<<1024, 256, 0, stream>>>(dst, cnt);
        scan_blocks<<<NSB, 1024, 0, stream>>>(cnt, base, part);
        scan_add<<<NSB, 1024, 0, stream>>>(base, part);
        scatter_kernel<<<1024, 256, 0, stream>>>(dst, src, base, cursor, meta);
        msg_agg_kernel_fb<<<6250, 256, 0, stream>>>(node_emb, meta, edge_emb, WtM,
                                                    b_msg, cnt, mean);
        node_kernel_fb<<<391, 256, 0, stream>>>(node_emb, mean, WtU, b_upd, out);
    }
}